// Round 8
// baseline (731.752 us; speedup 1.0000x reference)
//
#include <hip/hip_runtime.h>
#include <hip/hip_fp16.h>

#define NN 50000
#define NE 800000
#define NG 128
#define IND 5
#define HID 64
#define EPSV 1e-5f
#define SCAN_T 1024

// ---- dst histogram (counts at d+1) ----
__global__ void k_hist(const int* __restrict__ dst, int* row_ptr) {
    int e = blockIdx.x * blockDim.x + threadIdx.x;
    if (e < NE) atomicAdd(&row_ptr[dst[e] + 1], 1);
}

// ---- single-block inclusive scan of row_ptr[0..NN] ----
__global__ void k_scan(int* __restrict__ row_ptr) {
    __shared__ int tot[SCAN_T];
    int t = threadIdx.x;
    const int CH = (NN + 1 + SCAN_T - 1) / SCAN_T;
    int beg = t * CH;
    int end = beg + CH; if (end > NN + 1) end = NN + 1;
    int s = 0;
    for (int i = beg; i < end; i++) s += row_ptr[i];
    tot[t] = s;
    __syncthreads();
    for (int off = 1; off < SCAN_T; off <<= 1) {
        int v = (t >= off) ? tot[t - off] : 0;
        __syncthreads();
        tot[t] += v;
        __syncthreads();
    }
    int run = (t > 0) ? tot[t - 1] : 0;
    for (int i = beg; i < end; i++) { run += row_ptr[i]; row_ptr[i] = run; }
}

// ---- bin edges into CSR as (src, raw w) + parallel dst array ----
__global__ void k_fill_w(const int* __restrict__ src, const int* __restrict__ dst,
                         const float* __restrict__ ew,
                         const int* __restrict__ row_ptr, int* cursor,
                         int2* __restrict__ csr, int* __restrict__ cdst) {
    int e = blockIdx.x * blockDim.x + threadIdx.x;
    if (e >= NE) return;
    int s = src[e], d = dst[e];
    int pos = row_ptr[d] + atomicAdd(&cursor[d], 1);
    csr[pos] = make_int2(s, __float_as_int(ew[e]));
    cdst[pos] = d;
}

// ---- deg from CSR rows (sequential, no atomics): dinv = rsqrt(sum(w)+1) ----
__global__ void k_deg_dinv(const int* __restrict__ row_ptr, const int2* __restrict__ csr,
                           float* __restrict__ dinv) {
    int gid = blockIdx.x * blockDim.x + threadIdx.x;  // NN*4 threads
    if (gid >= NN * 4) return;
    int n = gid >> 2, l = gid & 3;
    int beg = row_ptr[n], end = row_ptr[n + 1];
    float s = 0.f;
    for (int i = beg + l; i < end; i += 4) s += __int_as_float(csr[i].y);
    s += __shfl_xor(s, 1);
    s += __shfl_xor(s, 2);
    if (l == 0) dinv[n] = rsqrtf(s + 1.0f);
}

// ---- px = dinv[n] * x[n], padded 5 -> 8 ----
__global__ void k_pad_scale_x(const float* __restrict__ x, const float* __restrict__ dinv,
                              float* __restrict__ px) {
    int n = blockIdx.x * blockDim.x + threadIdx.x;
    if (n >= NN) return;
    float di = dinv[n];
    float4 a, b;
    a.x = di * x[n * IND + 0]; a.y = di * x[n * IND + 1];
    a.z = di * x[n * IND + 2]; a.w = di * x[n * IND + 3];
    b.x = di * x[n * IND + 4]; b.y = 0.f; b.z = 0.f; b.w = 0.f;
    ((float4*)px)[n * 2 + 0] = a;
    ((float4*)px)[n * 2 + 1] = b;
}

// ---- layer-1 aggregation on pre-scaled raw x (R7-proven shape) ----
__global__ void k_gather_x(const float* __restrict__ px, const float* __restrict__ dinv,
                           const int* __restrict__ row_ptr, const int2* __restrict__ csr,
                           float* __restrict__ xa) {
    int gid = blockIdx.x * blockDim.x + threadIdx.x;  // NN*16 threads
    if (gid >= NN * 16) return;
    int n = gid >> 4, lane16 = gid & 15;
    const float4* p4 = (const float4*)px;
    int beg = row_ptr[n], end = row_ptr[n + 1];
    float4 a0 = make_float4(0.f, 0.f, 0.f, 0.f);
    float a4 = 0.f;
    int i = beg + lane16;
    if (i < end) {
        long long cur = __builtin_nontemporal_load((const long long*)&csr[i]);
        for (; i < end; i += 16) {
            int pi = (i + 16 < end) ? i + 16 : i;
            long long nxt = __builtin_nontemporal_load((const long long*)&csr[pi]);
            int   s = (int)(cur & 0xffffffffLL);
            float w = __int_as_float((int)(cur >> 32));
            float4 v0 = p4[s * 2 + 0];
            float  v4 = px[s * 8 + 4];
            a0.x += w * v0.x; a0.y += w * v0.y; a0.z += w * v0.z; a0.w += w * v0.w;
            a4 += w * v4;
            cur = nxt;
        }
    }
#pragma unroll
    for (int m = 8; m >= 1; m >>= 1) {
        a0.x += __shfl_xor(a0.x, m); a0.y += __shfl_xor(a0.y, m);
        a0.z += __shfl_xor(a0.z, m); a0.w += __shfl_xor(a0.w, m);
        a4 += __shfl_xor(a4, m);
    }
    if (lane16 == 0) {
        float di = dinv[n];
        float4 v0 = p4[n * 2 + 0];
        float  v4 = px[n * 8 + 4];
        float4 o0;
        o0.x = di * (a0.x + v0.x); o0.y = di * (a0.y + v0.y);
        o0.z = di * (a0.z + v0.z); o0.w = di * (a0.w + v0.w);
        ((float4*)xa)[n * 2 + 0] = o0;
        ((float4*)xa)[n * 2 + 1] = make_float4(di * (a4 + v4), 0.f, 0.f, 0.f);
    }
}

// ---- fused projection + bias + bn1 + relu ----
__global__ void k_gemm1_fused(const float* __restrict__ xa, const float* __restrict__ W1,
                              const float* __restrict__ b1,
                              const float* __restrict__ gamma, const float* __restrict__ beta,
                              const float* __restrict__ mean, const float* __restrict__ var,
                              float* __restrict__ outv) {
    __shared__ float Ws[IND * HID];
    for (int j = threadIdx.x; j < IND * HID; j += blockDim.x) Ws[j] = W1[j];
    __syncthreads();
    int gid = blockIdx.x * blockDim.x + threadIdx.x;
    if (gid >= NN * HID) return;
    int n = gid >> 6, hc = gid & 63;
    const float* xr = &xa[n * 8];
    float acc = b1[hc];
#pragma unroll
    for (int k = 0; k < IND; k++) acc += xr[k] * Ws[k * HID + hc];
    float r = fmaxf((acc - mean[hc]) * rsqrtf(var[hc] + EPSV) * gamma[hc] + beta[hc], 0.f);
    outv[gid] = r;
}

// ---- a @ W2, pre-scaled by dinv[n], fp16 full-width table (128 B/row) ----
__global__ void k_gemm2_h16(const float* __restrict__ a, const float* __restrict__ W,
                            const float* __restrict__ dinv, __half* __restrict__ tab) {
    __shared__ float Ws[HID * HID];
    for (int j = threadIdx.x; j < HID * HID; j += blockDim.x) Ws[j] = W[j];
    __syncthreads();
    int gid = blockIdx.x * blockDim.x + threadIdx.x;
    if (gid >= NN * HID) return;
    int n = gid >> 6, hc = gid & 63;
    const float* ar = &a[n * HID];
    float acc = 0.f;
#pragma unroll 8
    for (int k = 0; k < HID; k++) acc += ar[k] * Ws[k * HID + hc];
    tab[gid] = __float2half(dinv[n] * acc);
}

// ---- EDGE-PARALLEL layer-2 aggregation: no serial chains.
//      Wave = 8 edge-slots x 8 sublanes; lane loads uint4 (8 fp16 ch); 4 chunk
//      iterations (32 edges/wave). CSR is dst-sorted -> segmented inclusive
//      scan over slots + cross-iteration carry; only segment heads atomicAdd
//      into the zeroed fp32 accumulator bufB. ----
#define ECHUNK 32
__global__ void k_edge_gather(const __half* __restrict__ tab,
                              const int2* __restrict__ csr, const int* __restrict__ cdst,
                              float* __restrict__ bufB) {
    int wid = (blockIdx.x * blockDim.x + threadIdx.x) >> 6;
    int lane = threadIdx.x & 63;
    int slot = lane >> 3, sl = lane & 7;
    int base = wid * ECHUNK;
    if (base >= NE) return;                 // NE % ECHUNK == 0
    const uint4* hq = (const uint4*)tab;    // 8 uint4 per 64-ch row

    float carry[8];
#pragma unroll
    for (int j = 0; j < 8; j++) carry[j] = 0.f;
    int cd = -1;

    for (int it = 0; it < ECHUNK / 8; it++) {
        int e = base + it * 8 + slot;
        int2 ce = csr[e];                   // 8 sublanes same addr -> broadcast
        int d = cdst[e];
        float w = __int_as_float(ce.y);
        uint4 raw = hq[ce.x * 8 + sl];
        float v[8];
        float2 f;
        f = __half22float2(*(const __half2*)&raw.x); v[0] = w * f.x; v[1] = w * f.y;
        f = __half22float2(*(const __half2*)&raw.y); v[2] = w * f.x; v[3] = w * f.y;
        f = __half22float2(*(const __half2*)&raw.z); v[4] = w * f.x; v[5] = w * f.y;
        f = __half22float2(*(const __half2*)&raw.w); v[6] = w * f.x; v[7] = w * f.y;

        // segmented inclusive scan across slots (stride 8 = same sublane)
#pragma unroll
        for (int st = 1; st < 8; st <<= 1) {
            int od = __shfl_up(d, st * 8);
            float o0 = __shfl_up(v[0], st * 8), o1 = __shfl_up(v[1], st * 8);
            float o2 = __shfl_up(v[2], st * 8), o3 = __shfl_up(v[3], st * 8);
            float o4 = __shfl_up(v[4], st * 8), o5 = __shfl_up(v[5], st * 8);
            float o6 = __shfl_up(v[6], st * 8), o7 = __shfl_up(v[7], st * 8);
            if (slot >= st && od == d) {
                v[0] += o0; v[1] += o1; v[2] += o2; v[3] += o3;
                v[4] += o4; v[5] += o5; v[6] += o6; v[7] += o7;
            }
        }

        // carry handling (dst-sorted: carry either continues at slot 0 or is flushed)
        int d0 = __shfl(d, sl);             // dst of slot 0, same sublane
        if (it > 0 && d0 != cd) {
            if (slot == 0) {
                float* bp = &bufB[(long long)cd * HID + sl * 8];
#pragma unroll
                for (int j = 0; j < 8; j++) atomicAdd(bp + j, carry[j]);
            }
        } else if (d == cd) {
#pragma unroll
            for (int j = 0; j < 8; j++) v[j] += carry[j];
        }

        // heads: last slot of each segment except slot 7 (slot 7 becomes carry)
        int nd = __shfl_down(d, 8);
        bool head = (slot < 7) && (nd != d);
        if (head) {
            float* bp = &bufB[(long long)d * HID + sl * 8];
#pragma unroll
            for (int j = 0; j < 8; j++) atomicAdd(bp + j, v[j]);
        }

        // new carry = slot 7's (d, v), broadcast to all lanes
        cd = __shfl(d, 56 + sl);
#pragma unroll
        for (int j = 0; j < 8; j++) carry[j] = __shfl(v[j], 56 + sl);
    }
    // final flush
    if (slot == 0) {
        float* bp = &bufB[(long long)cd * HID + sl * 8];
#pragma unroll
        for (int j = 0; j < 8; j++) atomicAdd(bp + j, carry[j]);
    }
}

// ---- epilogue: out = dinv_d*(S + tab_d) + b2 -> bn2 -> relu -> pool ----
__global__ void k_bn_pool(const float* __restrict__ bufB, const __half* __restrict__ tab,
                          const float* __restrict__ dinv, const float* __restrict__ bias,
                          const float* __restrict__ gamma, const float* __restrict__ beta,
                          const float* __restrict__ mean, const float* __restrict__ var,
                          const int* __restrict__ batch,
                          float* pool, float* cnt) {
    int gid = blockIdx.x * blockDim.x + threadIdx.x;  // NN*16 float4 units
    if (gid >= NN * 16) return;
    int n = gid >> 4, c4 = gid & 15;
    int c0 = c4 * 4;
    float di = dinv[n];
    float4 S = ((const float4*)bufB)[gid];
    uint2 raw = ((const uint2*)tab)[gid];             // 4 fp16 ch (self, dinv_n-scaled)
    float2 t01 = __half22float2(*(const __half2*)&raw.x);
    float2 t23 = __half22float2(*(const __half2*)&raw.y);
    float v0 = di * (S.x + t01.x) + bias[c0 + 0];
    float v1 = di * (S.y + t01.y) + bias[c0 + 1];
    float v2 = di * (S.z + t23.x) + bias[c0 + 2];
    float v3 = di * (S.w + t23.y) + bias[c0 + 3];
    float r0 = fmaxf((v0 - mean[c0 + 0]) * rsqrtf(var[c0 + 0] + EPSV) * gamma[c0 + 0] + beta[c0 + 0], 0.f);
    float r1 = fmaxf((v1 - mean[c0 + 1]) * rsqrtf(var[c0 + 1] + EPSV) * gamma[c0 + 1] + beta[c0 + 1], 0.f);
    float r2 = fmaxf((v2 - mean[c0 + 2]) * rsqrtf(var[c0 + 2] + EPSV) * gamma[c0 + 2] + beta[c0 + 2], 0.f);
    float r3 = fmaxf((v3 - mean[c0 + 3]) * rsqrtf(var[c0 + 3] + EPSV) * gamma[c0 + 3] + beta[c0 + 3], 0.f);
    int g = batch[n];
    float* pp = &pool[g * HID + c0];
    atomicAdd(pp + 0, r0);
    atomicAdd(pp + 1, r1);
    atomicAdd(pp + 2, r2);
    atomicAdd(pp + 3, r3);
    if (c4 == 0) atomicAdd(&cnt[g], 1.0f);
}

// ---------------- final MLP ----------------
__global__ void k_mlp(const float* __restrict__ pool_sums, const float* __restrict__ cnt,
                      const float* __restrict__ l1W, const float* __restrict__ l1b,
                      const float* __restrict__ l2W, const float* __restrict__ l2b,
                      float* __restrict__ outp) {
    int g = blockIdx.x * blockDim.x + threadIdx.x;
    if (g >= NG) return;
    float c = fmaxf(cnt[g], 1.0f);
    float inv = 1.0f / c;
    float p[HID];
#pragma unroll
    for (int k = 0; k < HID; k++) p[k] = pool_sums[g * HID + k] * inv;
    float acc = 0.f;
    for (int j = 0; j < HID / 2; j++) {
        float z = l1b[j];
#pragma unroll 8
        for (int k = 0; k < HID; k++) z += p[k] * l1W[k * (HID / 2) + j];
        acc += fmaxf(z, 0.f) * l2W[j];
    }
    outp[g] = acc + l2b[0];
}

extern "C" void kernel_launch(void* const* d_in, const int* in_sizes, int n_in,
                              void* d_out, int out_size, void* d_ws, size_t ws_size,
                              hipStream_t stream) {
    const float* x   = (const float*)d_in[0];
    const int*   ei  = (const int*)d_in[1];
    const float* ew  = (const float*)d_in[2];
    const int*   bat = (const int*)d_in[3];
    const float* W1  = (const float*)d_in[4];
    const float* b1  = (const float*)d_in[5];
    const float* W2  = (const float*)d_in[6];
    const float* b2  = (const float*)d_in[7];
    const float* g1  = (const float*)d_in[8];
    const float* be1 = (const float*)d_in[9];
    const float* m1  = (const float*)d_in[10];
    const float* v1  = (const float*)d_in[11];
    const float* g2  = (const float*)d_in[12];
    const float* be2 = (const float*)d_in[13];
    const float* m2  = (const float*)d_in[14];
    const float* v2  = (const float*)d_in[15];
    const float* l1W = (const float*)d_in[16];
    const float* l1b = (const float*)d_in[17];
    const float* l2W = (const float*)d_in[18];
    const float* l2b = (const float*)d_in[19];
    float* out = (float*)d_out;

    const int* src = ei;
    const int* dst = ei + NE;

    // ---- workspace layout (4-byte units) ----
    float* f = (float*)d_ws;
    float* pool    = f + 0;                  // 8192
    float* cnt     = f + 8192;               // 128
    int*   row_ptr = (int*)(f + 8320);       // 50001
    int*   cursor  = (int*)(f + 58321);      // 50000
    // zero region = [0, 108321) floats
    int2*  csr     = (int2*)(f + 108328);    // 800000 int2 -> ends 1708328
    int*   cdst    = (int*)(f + 1708328);    // 800000
    float* dinv    = f + 2508328;            // 50000
    float* px      = f + 2558328;            // NN*8
    float* xa      = f + 2958328;            // NN*8
    float* bufC    = f + 3358328;            // NN*HID fp32 (layer-1 act); bufB aliases
    float* bufB    = f + 3358328;            //   (bufC dead after gemm2 reads it)
    __half* tab    = (__half*)(f + 6558328); // NN*HID fp16 -> ends 8158328 (32.6 MB)

    const int BLK = 256;
    const int gN   = (NN + BLK - 1) / BLK;
    const int gE   = (NE + BLK - 1) / BLK;
    const int gNH  = (NN * HID + BLK - 1) / BLK;
    const int gN16 = (NN * 16 + BLK - 1) / BLK;
    const int gN4  = (NN * 4 + BLK - 1) / BLK;
    const int gEW  = ((NE / ECHUNK) * 64 + BLK - 1) / BLK;  // one wave per 32 edges

    hipMemsetAsync(d_ws, 0, 108321 * sizeof(float), stream);

    // CSR build (dinv-free), then degree/dinv from CSR rows
    k_hist<<<gE, BLK, 0, stream>>>(dst, row_ptr);
    k_scan<<<1, SCAN_T, 0, stream>>>(row_ptr);
    k_fill_w<<<gE, BLK, 0, stream>>>(src, dst, ew, row_ptr, cursor, csr, cdst);
    k_deg_dinv<<<gN4, BLK, 0, stream>>>(row_ptr, csr, dinv);

    // layer 1: pre-scaled raw-x aggregation, then project (+bias+bn1+relu fused)
    k_pad_scale_x<<<gN, BLK, 0, stream>>>(x, dinv, px);
    k_gather_x<<<gN16, BLK, 0, stream>>>(px, dinv, row_ptr, csr, xa);
    k_gemm1_fused<<<gNH, BLK, 0, stream>>>(xa, W1, b1, g1, be1, m1, v1, bufC);

    // layer 2: project to pre-scaled fp16 table, edge-parallel aggregate, epilogue
    k_gemm2_h16<<<gNH, BLK, 0, stream>>>(bufC, W2, dinv, tab);
    hipMemsetAsync(bufB, 0, (size_t)NN * HID * sizeof(float), stream);  // after gemm2 read
    k_edge_gather<<<gEW, BLK, 0, stream>>>(tab, csr, cdst, bufB);
    k_bn_pool<<<gN16, BLK, 0, stream>>>(bufB, tab, dinv, b2,
                                        g2, be2, m2, v2, bat, pool, cnt);

    // MLP head
    k_mlp<<<1, 128, 0, stream>>>(pool, cnt, l1W, l1b, l2W, l2b, out);
}

// Round 9
// 340.909 us; speedup vs baseline: 2.1465x; 2.1465x over previous
//
#include <hip/hip_runtime.h>
#include <hip/hip_fp16.h>

#define NN 50000
#define NE 800000
#define NG 128
#define IND 5
#define HID 64
#define EPSV 1e-5f
#define SCAN_T 1024

// ---- dst histogram (counts at d+1) ----
__global__ void k_hist(const int* __restrict__ dst, int* row_ptr) {
    int e = blockIdx.x * blockDim.x + threadIdx.x;
    if (e < NE) atomicAdd(&row_ptr[dst[e] + 1], 1);
}

// ---- single-block inclusive scan of row_ptr[0..NN] ----
__global__ void k_scan(int* __restrict__ row_ptr) {
    __shared__ int tot[SCAN_T];
    int t = threadIdx.x;
    const int CH = (NN + 1 + SCAN_T - 1) / SCAN_T;
    int beg = t * CH;
    int end = beg + CH; if (end > NN + 1) end = NN + 1;
    int s = 0;
    for (int i = beg; i < end; i++) s += row_ptr[i];
    tot[t] = s;
    __syncthreads();
    for (int off = 1; off < SCAN_T; off <<= 1) {
        int v = (t >= off) ? tot[t - off] : 0;
        __syncthreads();
        tot[t] += v;
        __syncthreads();
    }
    int run = (t > 0) ? tot[t - 1] : 0;
    for (int i = beg; i < end; i++) { run += row_ptr[i]; row_ptr[i] = run; }
}

// ---- bin edges into CSR as (src, raw w) ----
__global__ void k_fill_w(const int* __restrict__ src, const int* __restrict__ dst,
                         const float* __restrict__ ew,
                         const int* __restrict__ row_ptr, int* cursor, int2* __restrict__ csr) {
    int e = blockIdx.x * blockDim.x + threadIdx.x;
    if (e >= NE) return;
    int s = src[e], d = dst[e];
    int pos = row_ptr[d] + atomicAdd(&cursor[d], 1);
    csr[pos] = make_int2(s, __float_as_int(ew[e]));
}

// ---- deg from CSR rows (sequential, no atomics): dinv = rsqrt(sum(w)+1) ----
__global__ void k_deg_dinv(const int* __restrict__ row_ptr, const int2* __restrict__ csr,
                           float* __restrict__ dinv) {
    int gid = blockIdx.x * blockDim.x + threadIdx.x;  // NN*4 threads
    if (gid >= NN * 4) return;
    int n = gid >> 2, l = gid & 3;
    int beg = row_ptr[n], end = row_ptr[n + 1];
    float s = 0.f;
    for (int i = beg + l; i < end; i += 4) s += __int_as_float(csr[i].y);
    s += __shfl_xor(s, 1);
    s += __shfl_xor(s, 2);
    if (l == 0) dinv[n] = rsqrtf(s + 1.0f);
}

// ---- px = dinv[n] * x[n], padded 5 -> 8 ----
__global__ void k_pad_scale_x(const float* __restrict__ x, const float* __restrict__ dinv,
                              float* __restrict__ px) {
    int n = blockIdx.x * blockDim.x + threadIdx.x;
    if (n >= NN) return;
    float di = dinv[n];
    float4 a, b;
    a.x = di * x[n * IND + 0]; a.y = di * x[n * IND + 1];
    a.z = di * x[n * IND + 2]; a.w = di * x[n * IND + 3];
    b.x = di * x[n * IND + 4]; b.y = 0.f; b.z = 0.f; b.w = 0.f;
    ((float4*)px)[n * 2 + 0] = a;
    ((float4*)px)[n * 2 + 1] = b;
}

// ---- layer-1 aggregation on pre-scaled raw x ----
__global__ void k_gather_x(const float* __restrict__ px, const float* __restrict__ dinv,
                           const int* __restrict__ row_ptr, const int2* __restrict__ csr,
                           float* __restrict__ xa) {
    int gid = blockIdx.x * blockDim.x + threadIdx.x;  // NN*16 threads
    if (gid >= NN * 16) return;
    int n = gid >> 4, lane16 = gid & 15;
    const float4* p4 = (const float4*)px;
    int beg = row_ptr[n], end = row_ptr[n + 1];
    float4 a0 = make_float4(0.f, 0.f, 0.f, 0.f);
    float a4 = 0.f;
    int i = beg + lane16;
    if (i < end) {
        long long cur = __builtin_nontemporal_load((const long long*)&csr[i]);
        for (; i < end; i += 16) {
            int pi = (i + 16 < end) ? i + 16 : i;
            long long nxt = __builtin_nontemporal_load((const long long*)&csr[pi]);
            int   s = (int)(cur & 0xffffffffLL);
            float w = __int_as_float((int)(cur >> 32));
            float4 v0 = p4[s * 2 + 0];
            float  v4 = px[s * 8 + 4];
            a0.x += w * v0.x; a0.y += w * v0.y; a0.z += w * v0.z; a0.w += w * v0.w;
            a4 += w * v4;
            cur = nxt;
        }
    }
#pragma unroll
    for (int m = 8; m >= 1; m >>= 1) {
        a0.x += __shfl_xor(a0.x, m); a0.y += __shfl_xor(a0.y, m);
        a0.z += __shfl_xor(a0.z, m); a0.w += __shfl_xor(a0.w, m);
        a4 += __shfl_xor(a4, m);
    }
    if (lane16 == 0) {
        float di = dinv[n];
        float4 v0 = p4[n * 2 + 0];
        float  v4 = px[n * 8 + 4];
        float4 o0;
        o0.x = di * (a0.x + v0.x); o0.y = di * (a0.y + v0.y);
        o0.z = di * (a0.z + v0.z); o0.w = di * (a0.w + v0.w);
        ((float4*)xa)[n * 2 + 0] = o0;
        ((float4*)xa)[n * 2 + 1] = make_float4(di * (a4 + v4), 0.f, 0.f, 0.f);
    }
}

// ---- fused projection + bias + bn1 + relu ----
__global__ void k_gemm1_fused(const float* __restrict__ xa, const float* __restrict__ W1,
                              const float* __restrict__ b1,
                              const float* __restrict__ gamma, const float* __restrict__ beta,
                              const float* __restrict__ mean, const float* __restrict__ var,
                              float* __restrict__ outv) {
    __shared__ float Ws[IND * HID];
    for (int j = threadIdx.x; j < IND * HID; j += blockDim.x) Ws[j] = W1[j];
    __syncthreads();
    int gid = blockIdx.x * blockDim.x + threadIdx.x;
    if (gid >= NN * HID) return;
    int n = gid >> 6, hc = gid & 63;
    const float* xr = &xa[n * 8];
    float acc = b1[hc];
#pragma unroll
    for (int k = 0; k < IND; k++) acc += xr[k] * Ws[k * HID + hc];
    float r = fmaxf((acc - mean[hc]) * rsqrtf(var[hc] + EPSV) * gamma[hc] + beta[hc], 0.f);
    outv[gid] = r;
}

// ---- a @ W2, pre-scaled by dinv[n], fp16 full-width table (128 B/row) ----
__global__ void k_gemm2_h16(const float* __restrict__ a, const float* __restrict__ W,
                            const float* __restrict__ dinv, __half* __restrict__ tab) {
    __shared__ float Ws[HID * HID];
    for (int j = threadIdx.x; j < HID * HID; j += blockDim.x) Ws[j] = W[j];
    __syncthreads();
    int gid = blockIdx.x * blockDim.x + threadIdx.x;
    if (gid >= NN * HID) return;
    int n = gid >> 6, hc = gid & 63;
    const float* ar = &a[n * HID];
    float acc = 0.f;
#pragma unroll 8
    for (int k = 0; k < HID; k++) acc += ar[k] * Ws[k * HID + hc];
    tab[gid] = __float2half(dinv[n] * acc);
}

// ---- layer-2 gather (R5-proven shape: 16 lanes/node, uint2/lane, 1-ahead csr
//      prefetch) + bn2 + relu, then PER-BLOCK LDS SEGMENTED POOL REDUCTION:
//      block = 16 consecutive nodes (batch sorted -> ~1 graph-segment/block);
//      64 channel-threads seg-reduce 16 node-rows in LDS -> ~1 atomic/ch/block
//      (pool atomics 3.2M -> ~210k; the 257us k_bn_pool contention wall). ----
__global__ void k_gather_pool(const __half* __restrict__ tab, const float* __restrict__ dinv,
                              const int* __restrict__ row_ptr, const int2* __restrict__ csr,
                              const float* __restrict__ bias,
                              const float* __restrict__ gamma, const float* __restrict__ beta,
                              const float* __restrict__ mean, const float* __restrict__ var,
                              const int* __restrict__ batch,
                              float* pool, float* cnt) {
    __shared__ float lds[16 * HID];   // 16 nodes x 64 ch
    __shared__ int gs[16];
    int tid = threadIdx.x;
    int gid = blockIdx.x * blockDim.x + tid;   // NN*16 threads exactly
    int n = gid >> 4, c4 = gid & 15;
    int nl = tid >> 4;
    if (tid < 16) gs[tid] = batch[blockIdx.x * 16 + tid];

    const uint2* hq = (const uint2*)tab;   // 16 uint2 (4 fp16 ch) per 64-ch row
    int beg = row_ptr[n], end = row_ptr[n + 1];

    // self row (pre-scaled by dinv_n)
    uint2 sraw = hq[n * 16 + c4];
    float2 s01 = __half22float2(*(const __half2*)&sraw.x);
    float2 s23 = __half22float2(*(const __half2*)&sraw.y);
    float a0 = s01.x, a1 = s01.y, a2 = s23.x, a3 = s23.y;

    if (beg < end) {
        long long cur = __builtin_nontemporal_load((const long long*)&csr[beg]);
        for (int i = beg; i < end; i++) {
            int pi = (i + 1 < end) ? i + 1 : i;
            long long nxt = __builtin_nontemporal_load((const long long*)&csr[pi]);
            int   s = (int)(cur & 0xffffffffLL);
            float w = __int_as_float((int)(cur >> 32));
            uint2 raw = hq[s * 16 + c4];
            float2 f01 = __half22float2(*(const __half2*)&raw.x);
            float2 f23 = __half22float2(*(const __half2*)&raw.y);
            a0 += w * f01.x; a1 += w * f01.y;
            a2 += w * f23.x; a3 += w * f23.y;
            cur = nxt;
        }
    }

    float di = dinv[n];
    int c0 = c4 * 4;
    float4 r;
    {
        float v0 = di * a0 + bias[c0 + 0];
        float v1 = di * a1 + bias[c0 + 1];
        float v2 = di * a2 + bias[c0 + 2];
        float v3 = di * a3 + bias[c0 + 3];
        r.x = fmaxf((v0 - mean[c0 + 0]) * rsqrtf(var[c0 + 0] + EPSV) * gamma[c0 + 0] + beta[c0 + 0], 0.f);
        r.y = fmaxf((v1 - mean[c0 + 1]) * rsqrtf(var[c0 + 1] + EPSV) * gamma[c0 + 1] + beta[c0 + 1], 0.f);
        r.z = fmaxf((v2 - mean[c0 + 2]) * rsqrtf(var[c0 + 2] + EPSV) * gamma[c0 + 2] + beta[c0 + 2], 0.f);
        r.w = fmaxf((v3 - mean[c0 + 3]) * rsqrtf(var[c0 + 3] + EPSV) * gamma[c0 + 3] + beta[c0 + 3], 0.f);
    }
    ((float4*)lds)[nl * 16 + c4] = r;
    __syncthreads();

    if (tid < HID) {
        int c = tid;
        float run = lds[0 * HID + c];
        int gprev = gs[0];
#pragma unroll
        for (int node = 1; node < 16; node++) {
            int g = gs[node];
            float v = lds[node * HID + c];
            if (g != gprev) { atomicAdd(&pool[gprev * HID + c], run); run = v; gprev = g; }
            else run += v;
        }
        atomicAdd(&pool[gprev * HID + c], run);
    } else if (tid == HID) {
        int run = 1, gprev = gs[0];
        for (int node = 1; node < 16; node++) {
            int g = gs[node];
            if (g != gprev) { atomicAdd(&cnt[gprev], (float)run); run = 0; gprev = g; }
            run++;
        }
        atomicAdd(&cnt[gprev], (float)run);
    }
}

// ---------------- final MLP ----------------
__global__ void k_mlp(const float* __restrict__ pool_sums, const float* __restrict__ cnt,
                      const float* __restrict__ l1W, const float* __restrict__ l1b,
                      const float* __restrict__ l2W, const float* __restrict__ l2b,
                      float* __restrict__ outp) {
    int g = blockIdx.x * blockDim.x + threadIdx.x;
    if (g >= NG) return;
    float c = fmaxf(cnt[g], 1.0f);
    float inv = 1.0f / c;
    float p[HID];
#pragma unroll
    for (int k = 0; k < HID; k++) p[k] = pool_sums[g * HID + k] * inv;
    float acc = 0.f;
    for (int j = 0; j < HID / 2; j++) {
        float z = l1b[j];
#pragma unroll 8
        for (int k = 0; k < HID; k++) z += p[k] * l1W[k * (HID / 2) + j];
        acc += fmaxf(z, 0.f) * l2W[j];
    }
    outp[g] = acc + l2b[0];
}

extern "C" void kernel_launch(void* const* d_in, const int* in_sizes, int n_in,
                              void* d_out, int out_size, void* d_ws, size_t ws_size,
                              hipStream_t stream) {
    const float* x   = (const float*)d_in[0];
    const int*   ei  = (const int*)d_in[1];
    const float* ew  = (const float*)d_in[2];
    const int*   bat = (const int*)d_in[3];
    const float* W1  = (const float*)d_in[4];
    const float* b1  = (const float*)d_in[5];
    const float* W2  = (const float*)d_in[6];
    const float* b2  = (const float*)d_in[7];
    const float* g1  = (const float*)d_in[8];
    const float* be1 = (const float*)d_in[9];
    const float* m1  = (const float*)d_in[10];
    const float* v1  = (const float*)d_in[11];
    const float* g2  = (const float*)d_in[12];
    const float* be2 = (const float*)d_in[13];
    const float* m2  = (const float*)d_in[14];
    const float* v2  = (const float*)d_in[15];
    const float* l1W = (const float*)d_in[16];
    const float* l1b = (const float*)d_in[17];
    const float* l2W = (const float*)d_in[18];
    const float* l2b = (const float*)d_in[19];
    float* out = (float*)d_out;

    const int* src = ei;
    const int* dst = ei + NE;

    // ---- workspace layout (4-byte units) ----
    float* f = (float*)d_ws;
    float* pool    = f + 0;                  // 8192
    float* cnt     = f + 8192;               // 128
    int*   row_ptr = (int*)(f + 8320);       // 50001
    int*   cursor  = (int*)(f + 58321);      // 50000
    // zero region = [0, 108321) floats
    int2*  csr     = (int2*)(f + 108328);    // 800000 int2 -> ends 1708328
    float* dinv    = f + 1708328;            // 50000
    float* px      = f + 1758328;            // NN*8
    float* xa      = f + 2158328;            // NN*8
    float* bufC    = f + 2558328;            // NN*HID fp32 (layer-1 act)
    __half* tab    = (__half*)(f + 5758328); // NN*HID fp16 -> ends 7358328 (29.4 MB)

    const int BLK = 256;
    const int gN   = (NN + BLK - 1) / BLK;
    const int gE   = (NE + BLK - 1) / BLK;
    const int gNH  = (NN * HID + BLK - 1) / BLK;
    const int gN16 = (NN * 16 + BLK - 1) / BLK;   // 3125 blocks = 16 nodes/block
    const int gN4  = (NN * 4 + BLK - 1) / BLK;

    hipMemsetAsync(d_ws, 0, 108321 * sizeof(float), stream);

    // CSR build (dinv-free), then degree/dinv from CSR rows
    k_hist<<<gE, BLK, 0, stream>>>(dst, row_ptr);
    k_scan<<<1, SCAN_T, 0, stream>>>(row_ptr);
    k_fill_w<<<gE, BLK, 0, stream>>>(src, dst, ew, row_ptr, cursor, csr);
    k_deg_dinv<<<gN4, BLK, 0, stream>>>(row_ptr, csr, dinv);

    // layer 1: pre-scaled raw-x aggregation, then project (+bias+bn1+relu fused)
    k_pad_scale_x<<<gN, BLK, 0, stream>>>(x, dinv, px);
    k_gather_x<<<gN16, BLK, 0, stream>>>(px, dinv, row_ptr, csr, xa);
    k_gemm1_fused<<<gNH, BLK, 0, stream>>>(xa, W1, b1, g1, be1, m1, v1, bufC);

    // layer 2: project to pre-scaled fp16 table, fused gather + bn2 + relu + LDS pool
    k_gemm2_h16<<<gNH, BLK, 0, stream>>>(bufC, W2, dinv, tab);
    k_gather_pool<<<gN16, BLK, 0, stream>>>(tab, dinv, row_ptr, csr, b2,
                                            g2, be2, m2, v2, bat, pool, cnt);

    // MLP head
    k_mlp<<<1, 128, 0, stream>>>(pool, cnt, l1W, l1b, l2W, l2b, out);
}

// Round 10
// 269.685 us; speedup vs baseline: 2.7134x; 1.2641x over previous
//
#include <hip/hip_runtime.h>
#include <hip/hip_fp16.h>

#define NN 50000
#define NE 800000
#define NG 128
#define IND 5
#define HID 64
#define EPSV 1e-5f
#define SCAN_BS 1024
#define NSB ((NN + 1 + SCAN_BS - 1) / SCAN_BS)   // 49 blocks

// ---- dst histogram (counts at d+1) ----
__global__ void k_hist(const int* __restrict__ dst, int* row_ptr) {
    int e = blockIdx.x * blockDim.x + threadIdx.x;
    if (e < NE) atomicAdd(&row_ptr[dst[e] + 1], 1);
}

// ---- hierarchical scan, stage 1: per-block LDS inclusive scan (in place)
//      + per-block totals.  49 blocks x 1024 (replaces the 79us 1-block scan). ----
__global__ void k_scan_blk(int* __restrict__ data, int* __restrict__ bsum) {
    __shared__ int sm[SCAN_BS];
    int t = threadIdx.x;
    int gid = blockIdx.x * SCAN_BS + t;
    int v = (gid <= NN) ? data[gid] : 0;
    sm[t] = v;
    __syncthreads();
    for (int off = 1; off < SCAN_BS; off <<= 1) {
        int o = (t >= off) ? sm[t - off] : 0;
        __syncthreads();
        sm[t] += o;
        __syncthreads();
    }
    if (gid <= NN) data[gid] = sm[t];
    if (t == SCAN_BS - 1) bsum[blockIdx.x] = sm[t];
}

// ---- stage 2: add exclusive prefix of block totals (NSB=49 <= 64 lanes) ----
__global__ void k_scan_fix(int* __restrict__ data, const int* __restrict__ bsum) {
    __shared__ int offs;
    int b = blockIdx.x, t = threadIdx.x;
    if (t < 64) {
        int s = (t < b) ? bsum[t] : 0;
#pragma unroll
        for (int m = 32; m >= 1; m >>= 1) s += __shfl_xor(s, m);
        if (t == 0) offs = s;
    }
    __syncthreads();
    int gid = b * SCAN_BS + t;
    if (b > 0 && gid <= NN) data[gid] += offs;
}

// ---- bin edges into CSR as (src, raw w) ----
__global__ void k_fill_w(const int* __restrict__ src, const int* __restrict__ dst,
                         const float* __restrict__ ew,
                         const int* __restrict__ row_ptr, int* cursor, int2* __restrict__ csr) {
    int e = blockIdx.x * blockDim.x + threadIdx.x;
    if (e >= NE) return;
    int s = src[e], d = dst[e];
    int pos = row_ptr[d] + atomicAdd(&cursor[d], 1);
    csr[pos] = make_int2(s, __float_as_int(ew[e]));
}

// ---- deg from CSR rows (sequential, no atomics): dinv = rsqrt(sum(w)+1) ----
__global__ void k_deg_dinv(const int* __restrict__ row_ptr, const int2* __restrict__ csr,
                           float* __restrict__ dinv) {
    int gid = blockIdx.x * blockDim.x + threadIdx.x;  // NN*4 threads
    if (gid >= NN * 4) return;
    int n = gid >> 2, l = gid & 3;
    int beg = row_ptr[n], end = row_ptr[n + 1];
    float s = 0.f;
    for (int i = beg + l; i < end; i += 4) s += __int_as_float(csr[i].y);
    s += __shfl_xor(s, 1);
    s += __shfl_xor(s, 2);
    if (l == 0) dinv[n] = rsqrtf(s + 1.0f);
}

// ---- px = dinv[n] * x[n], padded 5 -> 8 ----
__global__ void k_pad_scale_x(const float* __restrict__ x, const float* __restrict__ dinv,
                              float* __restrict__ px) {
    int n = blockIdx.x * blockDim.x + threadIdx.x;
    if (n >= NN) return;
    float di = dinv[n];
    float4 a, b;
    a.x = di * x[n * IND + 0]; a.y = di * x[n * IND + 1];
    a.z = di * x[n * IND + 2]; a.w = di * x[n * IND + 3];
    b.x = di * x[n * IND + 4]; b.y = 0.f; b.z = 0.f; b.w = 0.f;
    ((float4*)px)[n * 2 + 0] = a;
    ((float4*)px)[n * 2 + 1] = b;
}

// ---- layer-1 aggregation on pre-scaled raw x ----
__global__ void k_gather_x(const float* __restrict__ px, const float* __restrict__ dinv,
                           const int* __restrict__ row_ptr, const int2* __restrict__ csr,
                           float* __restrict__ xa) {
    int gid = blockIdx.x * blockDim.x + threadIdx.x;  // NN*16 threads
    if (gid >= NN * 16) return;
    int n = gid >> 4, lane16 = gid & 15;
    const float4* p4 = (const float4*)px;
    int beg = row_ptr[n], end = row_ptr[n + 1];
    float4 a0 = make_float4(0.f, 0.f, 0.f, 0.f);
    float a4 = 0.f;
    int i = beg + lane16;
    if (i < end) {
        long long cur = __builtin_nontemporal_load((const long long*)&csr[i]);
        for (; i < end; i += 16) {
            int pi = (i + 16 < end) ? i + 16 : i;
            long long nxt = __builtin_nontemporal_load((const long long*)&csr[pi]);
            int   s = (int)(cur & 0xffffffffLL);
            float w = __int_as_float((int)(cur >> 32));
            float4 v0 = p4[s * 2 + 0];
            float  v4 = px[s * 8 + 4];
            a0.x += w * v0.x; a0.y += w * v0.y; a0.z += w * v0.z; a0.w += w * v0.w;
            a4 += w * v4;
            cur = nxt;
        }
    }
#pragma unroll
    for (int m = 8; m >= 1; m >>= 1) {
        a0.x += __shfl_xor(a0.x, m); a0.y += __shfl_xor(a0.y, m);
        a0.z += __shfl_xor(a0.z, m); a0.w += __shfl_xor(a0.w, m);
        a4 += __shfl_xor(a4, m);
    }
    if (lane16 == 0) {
        float di = dinv[n];
        float4 v0 = p4[n * 2 + 0];
        float  v4 = px[n * 8 + 4];
        float4 o0;
        o0.x = di * (a0.x + v0.x); o0.y = di * (a0.y + v0.y);
        o0.z = di * (a0.z + v0.z); o0.w = di * (a0.w + v0.w);
        ((float4*)xa)[n * 2 + 0] = o0;
        ((float4*)xa)[n * 2 + 1] = make_float4(di * (a4 + v4), 0.f, 0.f, 0.f);
    }
}

// ---- fused projection + bias + bn1 + relu ----
__global__ void k_gemm1_fused(const float* __restrict__ xa, const float* __restrict__ W1,
                              const float* __restrict__ b1,
                              const float* __restrict__ gamma, const float* __restrict__ beta,
                              const float* __restrict__ mean, const float* __restrict__ var,
                              float* __restrict__ outv) {
    __shared__ float Ws[IND * HID];
    for (int j = threadIdx.x; j < IND * HID; j += blockDim.x) Ws[j] = W1[j];
    __syncthreads();
    int gid = blockIdx.x * blockDim.x + threadIdx.x;
    if (gid >= NN * HID) return;
    int n = gid >> 6, hc = gid & 63;
    const float* xr = &xa[n * 8];
    float acc = b1[hc];
#pragma unroll
    for (int k = 0; k < IND; k++) acc += xr[k] * Ws[k * HID + hc];
    float r = fmaxf((acc - mean[hc]) * rsqrtf(var[hc] + EPSV) * gamma[hc] + beta[hc], 0.f);
    outv[gid] = r;
}

// ---- a @ W2, pre-scaled by dinv[n], fp16 full-width table (128 B/row) ----
__global__ void k_gemm2_h16(const float* __restrict__ a, const float* __restrict__ W,
                            const float* __restrict__ dinv, __half* __restrict__ tab) {
    __shared__ float Ws[HID * HID];
    for (int j = threadIdx.x; j < HID * HID; j += blockDim.x) Ws[j] = W[j];
    __syncthreads();
    int gid = blockIdx.x * blockDim.x + threadIdx.x;
    if (gid >= NN * HID) return;
    int n = gid >> 6, hc = gid & 63;
    const float* ar = &a[n * HID];
    float acc = 0.f;
#pragma unroll 8
    for (int k = 0; k < HID; k++) acc += ar[k] * Ws[k * HID + hc];
    tab[gid] = __float2half(dinv[n] * acc);
}

// ---- layer-2 gather + bn2 + relu + per-block LDS segmented pool reduction ----
__global__ void k_gather_pool(const __half* __restrict__ tab, const float* __restrict__ dinv,
                              const int* __restrict__ row_ptr, const int2* __restrict__ csr,
                              const float* __restrict__ bias,
                              const float* __restrict__ gamma, const float* __restrict__ beta,
                              const float* __restrict__ mean, const float* __restrict__ var,
                              const int* __restrict__ batch,
                              float* pool, float* cnt) {
    __shared__ float lds[16 * HID];   // 16 nodes x 64 ch
    __shared__ int gs[16];
    int tid = threadIdx.x;
    int gid = blockIdx.x * blockDim.x + tid;   // NN*16 threads exactly
    int n = gid >> 4, c4 = gid & 15;
    int nl = tid >> 4;
    if (tid < 16) gs[tid] = batch[blockIdx.x * 16 + tid];

    const uint2* hq = (const uint2*)tab;   // 16 uint2 (4 fp16 ch) per 64-ch row
    int beg = row_ptr[n], end = row_ptr[n + 1];

    // self row (pre-scaled by dinv_n)
    uint2 sraw = hq[n * 16 + c4];
    float2 s01 = __half22float2(*(const __half2*)&sraw.x);
    float2 s23 = __half22float2(*(const __half2*)&sraw.y);
    float a0 = s01.x, a1 = s01.y, a2 = s23.x, a3 = s23.y;

    if (beg < end) {
        long long cur = __builtin_nontemporal_load((const long long*)&csr[beg]);
        for (int i = beg; i < end; i++) {
            int pi = (i + 1 < end) ? i + 1 : i;
            long long nxt = __builtin_nontemporal_load((const long long*)&csr[pi]);
            int   s = (int)(cur & 0xffffffffLL);
            float w = __int_as_float((int)(cur >> 32));
            uint2 raw = hq[s * 16 + c4];
            float2 f01 = __half22float2(*(const __half2*)&raw.x);
            float2 f23 = __half22float2(*(const __half2*)&raw.y);
            a0 += w * f01.x; a1 += w * f01.y;
            a2 += w * f23.x; a3 += w * f23.y;
            cur = nxt;
        }
    }

    float di = dinv[n];
    int c0 = c4 * 4;
    float4 r;
    {
        float v0 = di * a0 + bias[c0 + 0];
        float v1 = di * a1 + bias[c0 + 1];
        float v2 = di * a2 + bias[c0 + 2];
        float v3 = di * a3 + bias[c0 + 3];
        r.x = fmaxf((v0 - mean[c0 + 0]) * rsqrtf(var[c0 + 0] + EPSV) * gamma[c0 + 0] + beta[c0 + 0], 0.f);
        r.y = fmaxf((v1 - mean[c0 + 1]) * rsqrtf(var[c0 + 1] + EPSV) * gamma[c0 + 1] + beta[c0 + 1], 0.f);
        r.z = fmaxf((v2 - mean[c0 + 2]) * rsqrtf(var[c0 + 2] + EPSV) * gamma[c0 + 2] + beta[c0 + 2], 0.f);
        r.w = fmaxf((v3 - mean[c0 + 3]) * rsqrtf(var[c0 + 3] + EPSV) * gamma[c0 + 3] + beta[c0 + 3], 0.f);
    }
    ((float4*)lds)[nl * 16 + c4] = r;
    __syncthreads();

    if (tid < HID) {
        int c = tid;
        float run = lds[0 * HID + c];
        int gprev = gs[0];
#pragma unroll
        for (int node = 1; node < 16; node++) {
            int g = gs[node];
            float v = lds[node * HID + c];
            if (g != gprev) { atomicAdd(&pool[gprev * HID + c], run); run = v; gprev = g; }
            else run += v;
        }
        atomicAdd(&pool[gprev * HID + c], run);
    } else if (tid == HID) {
        int run = 1, gprev = gs[0];
        for (int node = 1; node < 16; node++) {
            int g = gs[node];
            if (g != gprev) { atomicAdd(&cnt[gprev], (float)run); run = 0; gprev = g; }
            run++;
        }
        atomicAdd(&cnt[gprev], (float)run);
    }
}

// ---------------- final MLP ----------------
__global__ void k_mlp(const float* __restrict__ pool_sums, const float* __restrict__ cnt,
                      const float* __restrict__ l1W, const float* __restrict__ l1b,
                      const float* __restrict__ l2W, const float* __restrict__ l2b,
                      float* __restrict__ outp) {
    int g = blockIdx.x * blockDim.x + threadIdx.x;
    if (g >= NG) return;
    float c = fmaxf(cnt[g], 1.0f);
    float inv = 1.0f / c;
    float p[HID];
#pragma unroll
    for (int k = 0; k < HID; k++) p[k] = pool_sums[g * HID + k] * inv;
    float acc = 0.f;
    for (int j = 0; j < HID / 2; j++) {
        float z = l1b[j];
#pragma unroll 8
        for (int k = 0; k < HID; k++) z += p[k] * l1W[k * (HID / 2) + j];
        acc += fmaxf(z, 0.f) * l2W[j];
    }
    outp[g] = acc + l2b[0];
}

extern "C" void kernel_launch(void* const* d_in, const int* in_sizes, int n_in,
                              void* d_out, int out_size, void* d_ws, size_t ws_size,
                              hipStream_t stream) {
    const float* x   = (const float*)d_in[0];
    const int*   ei  = (const int*)d_in[1];
    const float* ew  = (const float*)d_in[2];
    const int*   bat = (const int*)d_in[3];
    const float* W1  = (const float*)d_in[4];
    const float* b1  = (const float*)d_in[5];
    const float* W2  = (const float*)d_in[6];
    const float* b2  = (const float*)d_in[7];
    const float* g1  = (const float*)d_in[8];
    const float* be1 = (const float*)d_in[9];
    const float* m1  = (const float*)d_in[10];
    const float* v1  = (const float*)d_in[11];
    const float* g2  = (const float*)d_in[12];
    const float* be2 = (const float*)d_in[13];
    const float* m2  = (const float*)d_in[14];
    const float* v2  = (const float*)d_in[15];
    const float* l1W = (const float*)d_in[16];
    const float* l1b = (const float*)d_in[17];
    const float* l2W = (const float*)d_in[18];
    const float* l2b = (const float*)d_in[19];
    float* out = (float*)d_out;

    const int* src = ei;
    const int* dst = ei + NE;

    // ---- workspace layout (4-byte units) ----
    float* f = (float*)d_ws;
    float* pool    = f + 0;                  // 8192
    float* cnt     = f + 8192;               // 128
    int*   row_ptr = (int*)(f + 8320);       // 50001
    int*   cursor  = (int*)(f + 58321);      // 50000
    // zero region = [0, 108321) floats
    int*   bsum    = (int*)(f + 108321);     // 64 (written before read; no zeroing)
    int2*  csr     = (int2*)(f + 108392);    // 800000 int2 (8B aligned) -> ends 1708392
    float* dinv    = f + 1708392;            // 50000
    float* px      = f + 1758392;            // NN*8
    float* xa      = f + 2158392;            // NN*8
    float* bufC    = f + 2558392;            // NN*HID fp32 (layer-1 act)
    __half* tab    = (__half*)(f + 5758392); // NN*HID fp16 -> ends 7358392 (29.4 MB)

    const int BLK = 256;
    const int gN   = (NN + BLK - 1) / BLK;
    const int gE   = (NE + BLK - 1) / BLK;
    const int gNH  = (NN * HID + BLK - 1) / BLK;
    const int gN16 = (NN * 16 + BLK - 1) / BLK;   // 3125 blocks = 16 nodes/block
    const int gN4  = (NN * 4 + BLK - 1) / BLK;

    hipMemsetAsync(d_ws, 0, 108321 * sizeof(float), stream);

    // CSR build: hist -> hierarchical scan (2 kernels) -> fill -> deg/dinv
    k_hist<<<gE, BLK, 0, stream>>>(dst, row_ptr);
    k_scan_blk<<<NSB, SCAN_BS, 0, stream>>>(row_ptr, bsum);
    k_scan_fix<<<NSB, SCAN_BS, 0, stream>>>(row_ptr, bsum);
    k_fill_w<<<gE, BLK, 0, stream>>>(src, dst, ew, row_ptr, cursor, csr);
    k_deg_dinv<<<gN4, BLK, 0, stream>>>(row_ptr, csr, dinv);

    // layer 1: pre-scaled raw-x aggregation, then project (+bias+bn1+relu fused)
    k_pad_scale_x<<<gN, BLK, 0, stream>>>(x, dinv, px);
    k_gather_x<<<gN16, BLK, 0, stream>>>(px, dinv, row_ptr, csr, xa);
    k_gemm1_fused<<<gNH, BLK, 0, stream>>>(xa, W1, b1, g1, be1, m1, v1, bufC);

    // layer 2: project to pre-scaled fp16 table, fused gather + bn2 + relu + LDS pool
    k_gemm2_h16<<<gNH, BLK, 0, stream>>>(bufC, W2, dinv, tab);
    k_gather_pool<<<gN16, BLK, 0, stream>>>(tab, dinv, row_ptr, csr, b2,
                                            g2, be2, m2, v2, bat, pool, cnt);

    // MLP head
    k_mlp<<<1, 128, 0, stream>>>(pool, cnt, l1W, l1b, l2W, l2b, out);
}

// Round 11
// 225.206 us; speedup vs baseline: 3.2493x; 1.1975x over previous
//
#include <hip/hip_runtime.h>
#include <hip/hip_fp16.h>

#define NN 50000
#define NE 800000
#define NG 128
#define IND 5
#define HID 64
#define EPSV 1e-5f

#define NB 391          // buckets of 128 nodes: 391*128 = 50048 >= 50001
#define PH_T 1024       // partition wg size
#define PH_E 16384      // edges per partition wg (49 wgs)
#define PH_WG ((NE + PH_E - 1) / PH_E)

// ---- partition pass 1: per-bucket edge counts (LDS hist -> ~19k global atomics) ----
__global__ void k_part_hist(const int* __restrict__ dst, int* __restrict__ bkt_hist) {
    __shared__ int h[NB];
    int tid = threadIdx.x;
    for (int j = tid; j < NB; j += PH_T) h[j] = 0;
    __syncthreads();
    int base = blockIdx.x * PH_E;
    for (int k = 0; k < PH_E; k += PH_T) {
        int e = base + k + tid;
        if (e < NE) atomicAdd(&h[dst[e] >> 7], 1);
    }
    __syncthreads();
    for (int j = tid; j < NB; j += PH_T) if (h[j]) atomicAdd(&bkt_hist[j], h[j]);
}

// ---- tiny scan of 391 bucket counts -> exclusive bucket edge bases beb[0..391] ----
__global__ void k_bscan(const int* __restrict__ bkt_hist, int* __restrict__ beb) {
    __shared__ int sm[512];
    int t = threadIdx.x;
    sm[t] = (t < NB) ? bkt_hist[t] : 0;
    __syncthreads();
    for (int off = 1; off < 512; off <<= 1) {
        int v = (t >= off) ? sm[t - off] : 0;
        __syncthreads();
        sm[t] += v;
        __syncthreads();
    }
    if (t <= NB) beb[t] = t ? sm[t - 1] : 0;
}

// ---- partition pass 2: scatter edges into bucket-contiguous staging (int4:
//      src, w, dst).  Per-WG chunk reservation -> contiguous runs per bucket
//      -> coalesced writes (fixes fill_w's 52.7MB write-allocate amplification). ----
__global__ void k_part_scatter(const int* __restrict__ src, const int* __restrict__ dst,
                               const float* __restrict__ ew, const int* __restrict__ beb,
                               int* __restrict__ bkt_cursor, int4* __restrict__ stage) {
    __shared__ int c[NB];
    __shared__ int base[NB];
    __shared__ int cur[NB];
    int tid = threadIdx.x;
    for (int j = tid; j < NB; j += PH_T) { c[j] = 0; cur[j] = 0; }
    __syncthreads();
    int eb = blockIdx.x * PH_E;
    for (int k = 0; k < PH_E; k += PH_T) {
        int e = eb + k + tid;
        if (e < NE) atomicAdd(&c[dst[e] >> 7], 1);
    }
    __syncthreads();
    for (int j = tid; j < NB; j += PH_T) base[j] = c[j] ? atomicAdd(&bkt_cursor[j], c[j]) : 0;
    __syncthreads();
    for (int k = 0; k < PH_E; k += PH_T) {
        int e = eb + k + tid;
        if (e < NE) {
            int d = dst[e], b = d >> 7;
            int off = atomicAdd(&cur[b], 1);
            stage[beb[b] + base[b] + off] = make_int4(src[e], __float_as_int(ew[e]), d, 0);
        }
    }
}

// ---- bucket finalize: one WG per bucket (~2k edges, L2-hot 32KB region).
//      LDS 128-hist + scan -> row_ptr (no global scan), LDS float accum -> deg
//      -> dinv (+fused px = dinv*x pad), then in-window csr scatter. ----
__global__ void k_bucket_fill(const int4* __restrict__ stage, const int* __restrict__ beb,
                              const float* __restrict__ x,
                              int* __restrict__ row_ptr, int2* __restrict__ csr,
                              float* __restrict__ dinv, float* __restrict__ px) {
    __shared__ int cnt[128];
    __shared__ float deg[128];
    __shared__ int cur[128];
    __shared__ int sc[128];
    int b = blockIdx.x, tid = threadIdx.x;
    if (tid < 128) { cnt[tid] = 0; deg[tid] = 0.f; cur[tid] = 0; }
    __syncthreads();
    int eb0 = beb[b], eb1 = beb[b + 1];
    for (int i = eb0 + tid; i < eb1; i += 256) {
        int4 t = stage[i];
        int j = t.z & 127;
        atomicAdd(&cnt[j], 1);
        atomicAdd(&deg[j], __int_as_float(t.y));
    }
    __syncthreads();
    if (tid < 128) sc[tid] = cnt[tid];
    __syncthreads();
    for (int off = 1; off < 128; off <<= 1) {
        int v = 0;
        if (tid < 128 && tid >= off) v = sc[tid - off];
        __syncthreads();
        if (tid < 128) sc[tid] += v;
        __syncthreads();
    }
    if (tid < 128) {
        int n = b * 128 + tid;
        int ex = tid ? sc[tid - 1] : 0;
        if (n <= NN) row_ptr[n] = eb0 + ex;   // n==NN writes the end sentinel (=NE)
        if (n < NN) {
            float di = rsqrtf(deg[tid] + 1.0f);
            dinv[n] = di;
            float4 a, bb;
            a.x = di * x[n * IND + 0]; a.y = di * x[n * IND + 1];
            a.z = di * x[n * IND + 2]; a.w = di * x[n * IND + 3];
            bb.x = di * x[n * IND + 4]; bb.y = 0.f; bb.z = 0.f; bb.w = 0.f;
            ((float4*)px)[n * 2 + 0] = a;
            ((float4*)px)[n * 2 + 1] = bb;
        }
    }
    __syncthreads();
    for (int i = eb0 + tid; i < eb1; i += 256) {
        int4 t = stage[i];
        int j = t.z & 127;
        int ex = j ? sc[j - 1] : 0;
        int off = atomicAdd(&cur[j], 1);
        csr[eb0 + ex + off] = make_int2(t.x, t.y);
    }
}

// ---- layer-1 aggregation on pre-scaled raw x ----
__global__ void k_gather_x(const float* __restrict__ px, const float* __restrict__ dinv,
                           const int* __restrict__ row_ptr, const int2* __restrict__ csr,
                           float* __restrict__ xa) {
    int gid = blockIdx.x * blockDim.x + threadIdx.x;  // NN*16 threads
    if (gid >= NN * 16) return;
    int n = gid >> 4, lane16 = gid & 15;
    const float4* p4 = (const float4*)px;
    int beg = row_ptr[n], end = row_ptr[n + 1];
    float4 a0 = make_float4(0.f, 0.f, 0.f, 0.f);
    float a4 = 0.f;
    int i = beg + lane16;
    if (i < end) {
        long long cur = __builtin_nontemporal_load((const long long*)&csr[i]);
        for (; i < end; i += 16) {
            int pi = (i + 16 < end) ? i + 16 : i;
            long long nxt = __builtin_nontemporal_load((const long long*)&csr[pi]);
            int   s = (int)(cur & 0xffffffffLL);
            float w = __int_as_float((int)(cur >> 32));
            float4 v0 = p4[s * 2 + 0];
            float  v4 = px[s * 8 + 4];
            a0.x += w * v0.x; a0.y += w * v0.y; a0.z += w * v0.z; a0.w += w * v0.w;
            a4 += w * v4;
            cur = nxt;
        }
    }
#pragma unroll
    for (int m = 8; m >= 1; m >>= 1) {
        a0.x += __shfl_xor(a0.x, m); a0.y += __shfl_xor(a0.y, m);
        a0.z += __shfl_xor(a0.z, m); a0.w += __shfl_xor(a0.w, m);
        a4 += __shfl_xor(a4, m);
    }
    if (lane16 == 0) {
        float di = dinv[n];
        float4 v0 = p4[n * 2 + 0];
        float  v4 = px[n * 8 + 4];
        float4 o0;
        o0.x = di * (a0.x + v0.x); o0.y = di * (a0.y + v0.y);
        o0.z = di * (a0.z + v0.z); o0.w = di * (a0.w + v0.w);
        ((float4*)xa)[n * 2 + 0] = o0;
        ((float4*)xa)[n * 2 + 1] = make_float4(di * (a4 + v4), 0.f, 0.f, 0.f);
    }
}

// ---- fused projection + bias + bn1 + relu ----
__global__ void k_gemm1_fused(const float* __restrict__ xa, const float* __restrict__ W1,
                              const float* __restrict__ b1,
                              const float* __restrict__ gamma, const float* __restrict__ beta,
                              const float* __restrict__ mean, const float* __restrict__ var,
                              float* __restrict__ outv) {
    __shared__ float Ws[IND * HID];
    for (int j = threadIdx.x; j < IND * HID; j += blockDim.x) Ws[j] = W1[j];
    __syncthreads();
    int gid = blockIdx.x * blockDim.x + threadIdx.x;
    if (gid >= NN * HID) return;
    int n = gid >> 6, hc = gid & 63;
    const float* xr = &xa[n * 8];
    float acc = b1[hc];
#pragma unroll
    for (int k = 0; k < IND; k++) acc += xr[k] * Ws[k * HID + hc];
    float r = fmaxf((acc - mean[hc]) * rsqrtf(var[hc] + EPSV) * gamma[hc] + beta[hc], 0.f);
    outv[gid] = r;
}

// ---- a @ W2, pre-scaled by dinv[n], fp16 full-width table (128 B/row) ----
__global__ void k_gemm2_h16(const float* __restrict__ a, const float* __restrict__ W,
                            const float* __restrict__ dinv, __half* __restrict__ tab) {
    __shared__ float Ws[HID * HID];
    for (int j = threadIdx.x; j < HID * HID; j += blockDim.x) Ws[j] = W[j];
    __syncthreads();
    int gid = blockIdx.x * blockDim.x + threadIdx.x;
    if (gid >= NN * HID) return;
    int n = gid >> 6, hc = gid & 63;
    const float* ar = &a[n * HID];
    float acc = 0.f;
#pragma unroll 8
    for (int k = 0; k < HID; k++) acc += ar[k] * Ws[k * HID + hc];
    tab[gid] = __float2half(dinv[n] * acc);
}

// ---- layer-2 gather + bn2 + relu + per-block LDS segmented pool reduction ----
__global__ void k_gather_pool(const __half* __restrict__ tab, const float* __restrict__ dinv,
                              const int* __restrict__ row_ptr, const int2* __restrict__ csr,
                              const float* __restrict__ bias,
                              const float* __restrict__ gamma, const float* __restrict__ beta,
                              const float* __restrict__ mean, const float* __restrict__ var,
                              const int* __restrict__ batch,
                              float* pool, float* cnt) {
    __shared__ float lds[16 * HID];
    __shared__ int gs[16];
    int tid = threadIdx.x;
    int gid = blockIdx.x * blockDim.x + tid;   // NN*16 threads exactly
    int n = gid >> 4, c4 = gid & 15;
    int nl = tid >> 4;
    if (tid < 16) gs[tid] = batch[blockIdx.x * 16 + tid];

    const uint2* hq = (const uint2*)tab;
    int beg = row_ptr[n], end = row_ptr[n + 1];

    uint2 sraw = hq[n * 16 + c4];
    float2 s01 = __half22float2(*(const __half2*)&sraw.x);
    float2 s23 = __half22float2(*(const __half2*)&sraw.y);
    float a0 = s01.x, a1 = s01.y, a2 = s23.x, a3 = s23.y;

    if (beg < end) {
        long long cur = __builtin_nontemporal_load((const long long*)&csr[beg]);
        for (int i = beg; i < end; i++) {
            int pi = (i + 1 < end) ? i + 1 : i;
            long long nxt = __builtin_nontemporal_load((const long long*)&csr[pi]);
            int   s = (int)(cur & 0xffffffffLL);
            float w = __int_as_float((int)(cur >> 32));
            uint2 raw = hq[s * 16 + c4];
            float2 f01 = __half22float2(*(const __half2*)&raw.x);
            float2 f23 = __half22float2(*(const __half2*)&raw.y);
            a0 += w * f01.x; a1 += w * f01.y;
            a2 += w * f23.x; a3 += w * f23.y;
            cur = nxt;
        }
    }

    float di = dinv[n];
    int c0 = c4 * 4;
    float4 r;
    {
        float v0 = di * a0 + bias[c0 + 0];
        float v1 = di * a1 + bias[c0 + 1];
        float v2 = di * a2 + bias[c0 + 2];
        float v3 = di * a3 + bias[c0 + 3];
        r.x = fmaxf((v0 - mean[c0 + 0]) * rsqrtf(var[c0 + 0] + EPSV) * gamma[c0 + 0] + beta[c0 + 0], 0.f);
        r.y = fmaxf((v1 - mean[c0 + 1]) * rsqrtf(var[c0 + 1] + EPSV) * gamma[c0 + 1] + beta[c0 + 1], 0.f);
        r.z = fmaxf((v2 - mean[c0 + 2]) * rsqrtf(var[c0 + 2] + EPSV) * gamma[c0 + 2] + beta[c0 + 2], 0.f);
        r.w = fmaxf((v3 - mean[c0 + 3]) * rsqrtf(var[c0 + 3] + EPSV) * gamma[c0 + 3] + beta[c0 + 3], 0.f);
    }
    ((float4*)lds)[nl * 16 + c4] = r;
    __syncthreads();

    if (tid < HID) {
        int c = tid;
        float run = lds[0 * HID + c];
        int gprev = gs[0];
#pragma unroll
        for (int node = 1; node < 16; node++) {
            int g = gs[node];
            float v = lds[node * HID + c];
            if (g != gprev) { atomicAdd(&pool[gprev * HID + c], run); run = v; gprev = g; }
            else run += v;
        }
        atomicAdd(&pool[gprev * HID + c], run);
    } else if (tid == HID) {
        int run = 1, gprev = gs[0];
        for (int node = 1; node < 16; node++) {
            int g = gs[node];
            if (g != gprev) { atomicAdd(&cnt[gprev], (float)run); run = 0; gprev = g; }
            run++;
        }
        atomicAdd(&cnt[gprev], (float)run);
    }
}

// ---------------- final MLP ----------------
__global__ void k_mlp(const float* __restrict__ pool_sums, const float* __restrict__ cnt,
                      const float* __restrict__ l1W, const float* __restrict__ l1b,
                      const float* __restrict__ l2W, const float* __restrict__ l2b,
                      float* __restrict__ outp) {
    int g = blockIdx.x * blockDim.x + threadIdx.x;
    if (g >= NG) return;
    float c = fmaxf(cnt[g], 1.0f);
    float inv = 1.0f / c;
    float p[HID];
#pragma unroll
    for (int k = 0; k < HID; k++) p[k] = pool_sums[g * HID + k] * inv;
    float acc = 0.f;
    for (int j = 0; j < HID / 2; j++) {
        float z = l1b[j];
#pragma unroll 8
        for (int k = 0; k < HID; k++) z += p[k] * l1W[k * (HID / 2) + j];
        acc += fmaxf(z, 0.f) * l2W[j];
    }
    outp[g] = acc + l2b[0];
}

extern "C" void kernel_launch(void* const* d_in, const int* in_sizes, int n_in,
                              void* d_out, int out_size, void* d_ws, size_t ws_size,
                              hipStream_t stream) {
    const float* x   = (const float*)d_in[0];
    const int*   ei  = (const int*)d_in[1];
    const float* ew  = (const float*)d_in[2];
    const int*   bat = (const int*)d_in[3];
    const float* W1  = (const float*)d_in[4];
    const float* b1  = (const float*)d_in[5];
    const float* W2  = (const float*)d_in[6];
    const float* b2  = (const float*)d_in[7];
    const float* g1  = (const float*)d_in[8];
    const float* be1 = (const float*)d_in[9];
    const float* m1  = (const float*)d_in[10];
    const float* v1  = (const float*)d_in[11];
    const float* g2  = (const float*)d_in[12];
    const float* be2 = (const float*)d_in[13];
    const float* m2  = (const float*)d_in[14];
    const float* v2  = (const float*)d_in[15];
    const float* l1W = (const float*)d_in[16];
    const float* l1b = (const float*)d_in[17];
    const float* l2W = (const float*)d_in[18];
    const float* l2b = (const float*)d_in[19];
    float* out = (float*)d_out;

    const int* src = ei;
    const int* dst = ei + NE;

    // ---- workspace layout (4-byte units) ----
    float* f = (float*)d_ws;
    float* pool      = f + 0;                  // 8192
    float* cnt       = f + 8192;               // 128
    int*   bkt_hist  = (int*)(f + 8320);       // 391
    int*   bkt_cur   = (int*)(f + 8711);       // 391
    // zero region = [0, 9104) floats
    int*   beb       = (int*)(f + 9104);       // 392 (fully written by bscan)
    int*   row_ptr   = (int*)(f + 9496);       // 50001 (fully written by bucket_fill)
    int2*  csr       = (int2*)(f + 59500);     // 800000 int2 -> ends 1659500
    float* dinv      = f + 1659500;            // 50000
    float* px        = f + 1709500;            // NN*8 -> 2109500
    float* xa        = f + 2109500;            // NN*8 -> 2509500
    float* bufC      = f + 2509504;            // NN*HID fp32 (aliases stage; stage dead
    int4*  stage     = (int4*)(f + 2509504);   //  before gemm1 writes bufC) -> 5709504
    __half* tab      = (__half*)(f + 5709504); // NN*HID fp16 -> ends 7309504 (29.2 MB)

    const int BLK = 256;
    const int gNH  = (NN * HID + BLK - 1) / BLK;
    const int gN16 = (NN * 16 + BLK - 1) / BLK;   // 3125 blocks

    hipMemsetAsync(d_ws, 0, 9104 * sizeof(float), stream);

    // CSR build: bucket-partitioned (391 buckets x 128 nodes), all L2-local
    k_part_hist<<<PH_WG, PH_T, 0, stream>>>(dst, bkt_hist);
    k_bscan<<<1, 512, 0, stream>>>(bkt_hist, beb);
    k_part_scatter<<<PH_WG, PH_T, 0, stream>>>(src, dst, ew, beb, bkt_cur, stage);
    k_bucket_fill<<<NB, BLK, 0, stream>>>(stage, beb, x, row_ptr, csr, dinv, px);

    // layer 1: pre-scaled raw-x aggregation, then project (+bias+bn1+relu fused)
    k_gather_x<<<gN16, BLK, 0, stream>>>(px, dinv, row_ptr, csr, xa);
    k_gemm1_fused<<<gNH, BLK, 0, stream>>>(xa, W1, b1, g1, be1, m1, v1, bufC);

    // layer 2: project to pre-scaled fp16 table, fused gather + bn2 + relu + LDS pool
    k_gemm2_h16<<<gNH, BLK, 0, stream>>>(bufC, W2, dinv, tab);
    k_gather_pool<<<gN16, BLK, 0, stream>>>(tab, dinv, row_ptr, csr, b2,
                                            g2, be2, m2, v2, bat, pool, cnt);

    // MLP head
    k_mlp<<<1, 128, 0, stream>>>(pool, cnt, l1W, l1b, l2W, l2b, out);
}

// Round 12
// 179.430 us; speedup vs baseline: 4.0782x; 1.2551x over previous
//
#include <hip/hip_runtime.h>
#include <hip/hip_fp16.h>

#define NN 50000
#define NE 800000
#define NG 128
#define IND 5
#define HID 64
#define EPSV 1e-5f

#define NB 391          // buckets of 128 nodes: 391*128 = 50048 >= 50001
#define PH_T 1024       // partition wg size
#define PH_E 16384      // edges per partition wg (49 wgs)
#define PH_WG ((NE + PH_E - 1) / PH_E)

// ---- partition pass 1: per-bucket edge counts (LDS hist -> ~19k global atomics) ----
__global__ void k_part_hist(const int* __restrict__ dst, int* __restrict__ bkt_hist) {
    __shared__ int h[NB];
    int tid = threadIdx.x;
    for (int j = tid; j < NB; j += PH_T) h[j] = 0;
    __syncthreads();
    int base = blockIdx.x * PH_E;
    for (int k = 0; k < PH_E; k += PH_T) {
        int e = base + k + tid;
        if (e < NE) atomicAdd(&h[dst[e] >> 7], 1);
    }
    __syncthreads();
    for (int j = tid; j < NB; j += PH_T) if (h[j]) atomicAdd(&bkt_hist[j], h[j]);
}

// ---- tiny scan of 391 bucket counts -> exclusive bucket edge bases beb[0..391] ----
__global__ void k_bscan(const int* __restrict__ bkt_hist, int* __restrict__ beb) {
    __shared__ int sm[512];
    int t = threadIdx.x;
    sm[t] = (t < NB) ? bkt_hist[t] : 0;
    __syncthreads();
    for (int off = 1; off < 512; off <<= 1) {
        int v = (t >= off) ? sm[t - off] : 0;
        __syncthreads();
        sm[t] += v;
        __syncthreads();
    }
    if (t <= NB) beb[t] = t ? sm[t - 1] : 0;
}

// ---- partition pass 2: scatter edges into bucket-contiguous staging ----
__global__ void k_part_scatter(const int* __restrict__ src, const int* __restrict__ dst,
                               const float* __restrict__ ew, const int* __restrict__ beb,
                               int* __restrict__ bkt_cursor, int4* __restrict__ stage) {
    __shared__ int c[NB];
    __shared__ int base[NB];
    __shared__ int cur[NB];
    int tid = threadIdx.x;
    for (int j = tid; j < NB; j += PH_T) { c[j] = 0; cur[j] = 0; }
    __syncthreads();
    int eb = blockIdx.x * PH_E;
    for (int k = 0; k < PH_E; k += PH_T) {
        int e = eb + k + tid;
        if (e < NE) atomicAdd(&c[dst[e] >> 7], 1);
    }
    __syncthreads();
    for (int j = tid; j < NB; j += PH_T) base[j] = c[j] ? atomicAdd(&bkt_cursor[j], c[j]) : 0;
    __syncthreads();
    for (int k = 0; k < PH_E; k += PH_T) {
        int e = eb + k + tid;
        if (e < NE) {
            int d = dst[e], b = d >> 7;
            int off = atomicAdd(&cur[b], 1);
            stage[beb[b] + base[b] + off] = make_int4(src[e], __float_as_int(ew[e]), d, 0);
        }
    }
}

// ---- bucket finalize: row_ptr + dinv + px + in-window csr scatter ----
__global__ void k_bucket_fill(const int4* __restrict__ stage, const int* __restrict__ beb,
                              const float* __restrict__ x,
                              int* __restrict__ row_ptr, int2* __restrict__ csr,
                              float* __restrict__ dinv, float* __restrict__ px) {
    __shared__ int cnt[128];
    __shared__ float deg[128];
    __shared__ int cur[128];
    __shared__ int sc[128];
    int b = blockIdx.x, tid = threadIdx.x;
    if (tid < 128) { cnt[tid] = 0; deg[tid] = 0.f; cur[tid] = 0; }
    __syncthreads();
    int eb0 = beb[b], eb1 = beb[b + 1];
    for (int i = eb0 + tid; i < eb1; i += 256) {
        int4 t = stage[i];
        int j = t.z & 127;
        atomicAdd(&cnt[j], 1);
        atomicAdd(&deg[j], __int_as_float(t.y));
    }
    __syncthreads();
    if (tid < 128) sc[tid] = cnt[tid];
    __syncthreads();
    for (int off = 1; off < 128; off <<= 1) {
        int v = 0;
        if (tid < 128 && tid >= off) v = sc[tid - off];
        __syncthreads();
        if (tid < 128) sc[tid] += v;
        __syncthreads();
    }
    if (tid < 128) {
        int n = b * 128 + tid;
        int ex = tid ? sc[tid - 1] : 0;
        if (n <= NN) row_ptr[n] = eb0 + ex;   // n==NN writes the end sentinel (=NE)
        if (n < NN) {
            float di = rsqrtf(deg[tid] + 1.0f);
            dinv[n] = di;
            float4 a, bb;
            a.x = di * x[n * IND + 0]; a.y = di * x[n * IND + 1];
            a.z = di * x[n * IND + 2]; a.w = di * x[n * IND + 3];
            bb.x = di * x[n * IND + 4]; bb.y = 0.f; bb.z = 0.f; bb.w = 0.f;
            ((float4*)px)[n * 2 + 0] = a;
            ((float4*)px)[n * 2 + 1] = bb;
        }
    }
    __syncthreads();
    for (int i = eb0 + tid; i < eb1; i += 256) {
        int4 t = stage[i];
        int j = t.z & 127;
        int ex = j ? sc[j - 1] : 0;
        int off = atomicAdd(&cur[j], 1);
        csr[eb0 + ex + off] = make_int2(t.x, t.y);
    }
}

// ---- layer-1 aggregation on pre-scaled raw x ----
__global__ void k_gather_x(const float* __restrict__ px, const float* __restrict__ dinv,
                           const int* __restrict__ row_ptr, const int2* __restrict__ csr,
                           float* __restrict__ xa) {
    int gid = blockIdx.x * blockDim.x + threadIdx.x;  // NN*16 threads
    if (gid >= NN * 16) return;
    int n = gid >> 4, lane16 = gid & 15;
    const float4* p4 = (const float4*)px;
    int beg = row_ptr[n], end = row_ptr[n + 1];
    float4 a0 = make_float4(0.f, 0.f, 0.f, 0.f);
    float a4 = 0.f;
    int i = beg + lane16;
    if (i < end) {
        long long cur = __builtin_nontemporal_load((const long long*)&csr[i]);
        for (; i < end; i += 16) {
            int pi = (i + 16 < end) ? i + 16 : i;
            long long nxt = __builtin_nontemporal_load((const long long*)&csr[pi]);
            int   s = (int)(cur & 0xffffffffLL);
            float w = __int_as_float((int)(cur >> 32));
            float4 v0 = p4[s * 2 + 0];
            float  v4 = px[s * 8 + 4];
            a0.x += w * v0.x; a0.y += w * v0.y; a0.z += w * v0.z; a0.w += w * v0.w;
            a4 += w * v4;
            cur = nxt;
        }
    }
#pragma unroll
    for (int m = 8; m >= 1; m >>= 1) {
        a0.x += __shfl_xor(a0.x, m); a0.y += __shfl_xor(a0.y, m);
        a0.z += __shfl_xor(a0.z, m); a0.w += __shfl_xor(a0.w, m);
        a4 += __shfl_xor(a4, m);
    }
    if (lane16 == 0) {
        float di = dinv[n];
        float4 v0 = p4[n * 2 + 0];
        float  v4 = px[n * 8 + 4];
        float4 o0;
        o0.x = di * (a0.x + v0.x); o0.y = di * (a0.y + v0.y);
        o0.z = di * (a0.z + v0.z); o0.w = di * (a0.w + v0.w);
        ((float4*)xa)[n * 2 + 0] = o0;
        ((float4*)xa)[n * 2 + 1] = make_float4(di * (a4 + v4), 0.f, 0.f, 0.f);
    }
}

// ---- fused projection + bias + bn1 + relu ----
__global__ void k_gemm1_fused(const float* __restrict__ xa, const float* __restrict__ W1,
                              const float* __restrict__ b1,
                              const float* __restrict__ gamma, const float* __restrict__ beta,
                              const float* __restrict__ mean, const float* __restrict__ var,
                              float* __restrict__ outv) {
    __shared__ float Ws[IND * HID];
    for (int j = threadIdx.x; j < IND * HID; j += blockDim.x) Ws[j] = W1[j];
    __syncthreads();
    int gid = blockIdx.x * blockDim.x + threadIdx.x;
    if (gid >= NN * HID) return;
    int n = gid >> 6, hc = gid & 63;
    const float* xr = &xa[n * 8];
    float acc = b1[hc];
#pragma unroll
    for (int k = 0; k < IND; k++) acc += xr[k] * Ws[k * HID + hc];
    float r = fmaxf((acc - mean[hc]) * rsqrtf(var[hc] + EPSV) * gamma[hc] + beta[hc], 0.f);
    outv[gid] = r;
}

// ---- a @ W2, pre-scaled by dinv[n], fp16 full-width table (128 B/row) ----
__global__ void k_gemm2_h16(const float* __restrict__ a, const float* __restrict__ W,
                            const float* __restrict__ dinv, __half* __restrict__ tab) {
    __shared__ float Ws[HID * HID];
    for (int j = threadIdx.x; j < HID * HID; j += blockDim.x) Ws[j] = W[j];
    __syncthreads();
    int gid = blockIdx.x * blockDim.x + threadIdx.x;
    if (gid >= NN * HID) return;
    int n = gid >> 6, hc = gid & 63;
    const float* ar = &a[n * HID];
    float acc = 0.f;
#pragma unroll 8
    for (int k = 0; k < HID; k++) acc += ar[k] * Ws[k * HID + hc];
    tab[gid] = __float2half(dinv[n] * acc);
}

// ---- layer-2 gather + bn2 + relu + per-block LDS segmented pool reduction ----
__global__ void k_gather_pool(const __half* __restrict__ tab, const float* __restrict__ dinv,
                              const int* __restrict__ row_ptr, const int2* __restrict__ csr,
                              const float* __restrict__ bias,
                              const float* __restrict__ gamma, const float* __restrict__ beta,
                              const float* __restrict__ mean, const float* __restrict__ var,
                              const int* __restrict__ batch,
                              float* pool, float* cnt) {
    __shared__ float lds[16 * HID];
    __shared__ int gs[16];
    int tid = threadIdx.x;
    int gid = blockIdx.x * blockDim.x + tid;   // NN*16 threads exactly
    int n = gid >> 4, c4 = gid & 15;
    int nl = tid >> 4;
    if (tid < 16) gs[tid] = batch[blockIdx.x * 16 + tid];

    const uint2* hq = (const uint2*)tab;
    int beg = row_ptr[n], end = row_ptr[n + 1];

    uint2 sraw = hq[n * 16 + c4];
    float2 s01 = __half22float2(*(const __half2*)&sraw.x);
    float2 s23 = __half22float2(*(const __half2*)&sraw.y);
    float a0 = s01.x, a1 = s01.y, a2 = s23.x, a3 = s23.y;

    if (beg < end) {
        long long cur = __builtin_nontemporal_load((const long long*)&csr[beg]);
        for (int i = beg; i < end; i++) {
            int pi = (i + 1 < end) ? i + 1 : i;
            long long nxt = __builtin_nontemporal_load((const long long*)&csr[pi]);
            int   s = (int)(cur & 0xffffffffLL);
            float w = __int_as_float((int)(cur >> 32));
            uint2 raw = hq[s * 16 + c4];
            float2 f01 = __half22float2(*(const __half2*)&raw.x);
            float2 f23 = __half22float2(*(const __half2*)&raw.y);
            a0 += w * f01.x; a1 += w * f01.y;
            a2 += w * f23.x; a3 += w * f23.y;
            cur = nxt;
        }
    }

    float di = dinv[n];
    int c0 = c4 * 4;
    float4 r;
    {
        float v0 = di * a0 + bias[c0 + 0];
        float v1 = di * a1 + bias[c0 + 1];
        float v2 = di * a2 + bias[c0 + 2];
        float v3 = di * a3 + bias[c0 + 3];
        r.x = fmaxf((v0 - mean[c0 + 0]) * rsqrtf(var[c0 + 0] + EPSV) * gamma[c0 + 0] + beta[c0 + 0], 0.f);
        r.y = fmaxf((v1 - mean[c0 + 1]) * rsqrtf(var[c0 + 1] + EPSV) * gamma[c0 + 1] + beta[c0 + 1], 0.f);
        r.z = fmaxf((v2 - mean[c0 + 2]) * rsqrtf(var[c0 + 2] + EPSV) * gamma[c0 + 2] + beta[c0 + 2], 0.f);
        r.w = fmaxf((v3 - mean[c0 + 3]) * rsqrtf(var[c0 + 3] + EPSV) * gamma[c0 + 3] + beta[c0 + 3], 0.f);
    }
    ((float4*)lds)[nl * 16 + c4] = r;
    __syncthreads();

    if (tid < HID) {
        int c = tid;
        float run = lds[0 * HID + c];
        int gprev = gs[0];
#pragma unroll
        for (int node = 1; node < 16; node++) {
            int g = gs[node];
            float v = lds[node * HID + c];
            if (g != gprev) { atomicAdd(&pool[gprev * HID + c], run); run = v; gprev = g; }
            else run += v;
        }
        atomicAdd(&pool[gprev * HID + c], run);
    } else if (tid == HID) {
        int run = 1, gprev = gs[0];
        for (int node = 1; node < 16; node++) {
            int g = gs[node];
            if (g != gprev) { atomicAdd(&cnt[gprev], (float)run); run = 0; gprev = g; }
            run++;
        }
        atomicAdd(&cnt[gprev], (float)run);
    }
}

// ---- final MLP: one wave per graph.  lane=(j=lane&31, kh=lane>>5); each lane
//      32 coalesced FMAs over its k-half; shfl_xor(32) joins halves; butterfly
//      over j.  (Replaces the 54us 1-block serial version: 2048 stride-128B
//      loads/thread on one CU.) ----
__global__ void k_mlp(const float* __restrict__ pool_sums, const float* __restrict__ cnt,
                      const float* __restrict__ l1W, const float* __restrict__ l1b,
                      const float* __restrict__ l2W, const float* __restrict__ l2b,
                      float* __restrict__ outp) {
    int g = blockIdx.x;
    int lane = threadIdx.x;           // 64
    int j = lane & 31, kh = lane >> 5;
    const float* pg = &pool_sums[g * HID];
    float z = 0.f;
#pragma unroll 8
    for (int k = kh * 32; k < kh * 32 + 32; k++)
        z += pg[k] * l1W[k * (HID / 2) + j];
    z += __shfl_xor(z, 32);           // join k-halves
    float inv = 1.0f / fmaxf(cnt[g], 1.0f);
    float acc = (kh == 0) ? fmaxf(z * inv + l1b[j], 0.f) * l2W[j] : 0.f;
#pragma unroll
    for (int m = 16; m >= 1; m >>= 1) acc += __shfl_xor(acc, m);
    if (lane == 0) outp[g] = acc + l2b[0];
}

extern "C" void kernel_launch(void* const* d_in, const int* in_sizes, int n_in,
                              void* d_out, int out_size, void* d_ws, size_t ws_size,
                              hipStream_t stream) {
    const float* x   = (const float*)d_in[0];
    const int*   ei  = (const int*)d_in[1];
    const float* ew  = (const float*)d_in[2];
    const int*   bat = (const int*)d_in[3];
    const float* W1  = (const float*)d_in[4];
    const float* b1  = (const float*)d_in[5];
    const float* W2  = (const float*)d_in[6];
    const float* b2  = (const float*)d_in[7];
    const float* g1  = (const float*)d_in[8];
    const float* be1 = (const float*)d_in[9];
    const float* m1  = (const float*)d_in[10];
    const float* v1  = (const float*)d_in[11];
    const float* g2  = (const float*)d_in[12];
    const float* be2 = (const float*)d_in[13];
    const float* m2  = (const float*)d_in[14];
    const float* v2  = (const float*)d_in[15];
    const float* l1W = (const float*)d_in[16];
    const float* l1b = (const float*)d_in[17];
    const float* l2W = (const float*)d_in[18];
    const float* l2b = (const float*)d_in[19];
    float* out = (float*)d_out;

    const int* src = ei;
    const int* dst = ei + NE;

    // ---- workspace layout (4-byte units) ----
    float* f = (float*)d_ws;
    float* pool      = f + 0;                  // 8192
    float* cnt       = f + 8192;               // 128
    int*   bkt_hist  = (int*)(f + 8320);       // 391
    int*   bkt_cur   = (int*)(f + 8711);       // 391
    // zero region = [0, 9104) floats
    int*   beb       = (int*)(f + 9104);       // 392 (fully written by bscan)
    int*   row_ptr   = (int*)(f + 9496);       // 50001 (fully written by bucket_fill)
    int2*  csr       = (int2*)(f + 59500);     // 800000 int2 -> ends 1659500
    float* dinv      = f + 1659500;            // 50000
    float* px        = f + 1709500;            // NN*8 -> 2109500
    float* xa        = f + 2109500;            // NN*8 -> 2509500
    float* bufC      = f + 2509504;            // NN*HID fp32 (aliases stage; stage dead
    int4*  stage     = (int4*)(f + 2509504);   //  before gemm1 writes bufC) -> 5709504
    __half* tab      = (__half*)(f + 5709504); // NN*HID fp16 -> ends 7309504 (29.2 MB)

    const int BLK = 256;
    const int gNH  = (NN * HID + BLK - 1) / BLK;
    const int gN16 = (NN * 16 + BLK - 1) / BLK;   // 3125 blocks

    hipMemsetAsync(d_ws, 0, 9104 * sizeof(float), stream);

    // CSR build: bucket-partitioned (391 buckets x 128 nodes), all L2-local
    k_part_hist<<<PH_WG, PH_T, 0, stream>>>(dst, bkt_hist);
    k_bscan<<<1, 512, 0, stream>>>(bkt_hist, beb);
    k_part_scatter<<<PH_WG, PH_T, 0, stream>>>(src, dst, ew, beb, bkt_cur, stage);
    k_bucket_fill<<<NB, BLK, 0, stream>>>(stage, beb, x, row_ptr, csr, dinv, px);

    // layer 1: pre-scaled raw-x aggregation, then project (+bias+bn1+relu fused)
    k_gather_x<<<gN16, BLK, 0, stream>>>(px, dinv, row_ptr, csr, xa);
    k_gemm1_fused<<<gNH, BLK, 0, stream>>>(xa, W1, b1, g1, be1, m1, v1, bufC);

    // layer 2: project to pre-scaled fp16 table, fused gather + bn2 + relu + LDS pool
    k_gemm2_h16<<<gNH, BLK, 0, stream>>>(bufC, W2, dinv, tab);
    k_gather_pool<<<gN16, BLK, 0, stream>>>(tab, dinv, row_ptr, csr, b2,
                                            g2, be2, m2, v2, bat, pool, cnt);

    // MLP head: one wave per graph
    k_mlp<<<NG, 64, 0, stream>>>(pool, cnt, l1W, l1b, l2W, l2b, out);
}

// Round 13
// 165.780 us; speedup vs baseline: 4.4140x; 1.0823x over previous
//
#include <hip/hip_runtime.h>
#include <hip/hip_fp16.h>

#define NN 50000
#define NE 800000
#define NG 128
#define IND 5
#define HID 64
#define EPSV 1e-5f

#define NB 391          // buckets of 128 nodes: 391*128 = 50048 >= 50001
#define PH_T 1024       // partition wg size
#define PH_E 16384      // edges per partition wg (49 wgs)
#define PH_WG ((NE + PH_E - 1) / PH_E)

// ---- partition pass 1: per-bucket edge counts (LDS hist -> ~19k global atomics) ----
__global__ void k_part_hist(const int* __restrict__ dst, int* __restrict__ bkt_hist) {
    __shared__ int h[NB];
    int tid = threadIdx.x;
    for (int j = tid; j < NB; j += PH_T) h[j] = 0;
    __syncthreads();
    int base = blockIdx.x * PH_E;
    for (int k = 0; k < PH_E; k += PH_T) {
        int e = base + k + tid;
        if (e < NE) atomicAdd(&h[dst[e] >> 7], 1);
    }
    __syncthreads();
    for (int j = tid; j < NB; j += PH_T) if (h[j]) atomicAdd(&bkt_hist[j], h[j]);
}

// ---- tiny scan of 391 bucket counts -> exclusive bucket edge bases beb[0..391] ----
__global__ void k_bscan(const int* __restrict__ bkt_hist, int* __restrict__ beb) {
    __shared__ int sm[512];
    int t = threadIdx.x;
    sm[t] = (t < NB) ? bkt_hist[t] : 0;
    __syncthreads();
    for (int off = 1; off < 512; off <<= 1) {
        int v = (t >= off) ? sm[t - off] : 0;
        __syncthreads();
        sm[t] += v;
        __syncthreads();
    }
    if (t <= NB) beb[t] = t ? sm[t - 1] : 0;
}

// ---- partition pass 2: scatter edges into bucket-contiguous staging ----
__global__ void k_part_scatter(const int* __restrict__ src, const int* __restrict__ dst,
                               const float* __restrict__ ew, const int* __restrict__ beb,
                               int* __restrict__ bkt_cursor, int4* __restrict__ stage) {
    __shared__ int c[NB];
    __shared__ int base[NB];
    __shared__ int cur[NB];
    int tid = threadIdx.x;
    for (int j = tid; j < NB; j += PH_T) { c[j] = 0; cur[j] = 0; }
    __syncthreads();
    int eb = blockIdx.x * PH_E;
    for (int k = 0; k < PH_E; k += PH_T) {
        int e = eb + k + tid;
        if (e < NE) atomicAdd(&c[dst[e] >> 7], 1);
    }
    __syncthreads();
    for (int j = tid; j < NB; j += PH_T) base[j] = c[j] ? atomicAdd(&bkt_cursor[j], c[j]) : 0;
    __syncthreads();
    for (int k = 0; k < PH_E; k += PH_T) {
        int e = eb + k + tid;
        if (e < NE) {
            int d = dst[e], b = d >> 7;
            int off = atomicAdd(&cur[b], 1);
            stage[beb[b] + base[b] + off] = make_int4(src[e], __float_as_int(ew[e]), d, 0);
        }
    }
}

// ---- bucket finalize: row_ptr + dinv + px + in-window csr scatter ----
__global__ void k_bucket_fill(const int4* __restrict__ stage, const int* __restrict__ beb,
                              const float* __restrict__ x,
                              int* __restrict__ row_ptr, int2* __restrict__ csr,
                              float* __restrict__ dinv, float* __restrict__ px) {
    __shared__ int cnt[128];
    __shared__ float deg[128];
    __shared__ int cur[128];
    __shared__ int sc[128];
    int b = blockIdx.x, tid = threadIdx.x;
    if (tid < 128) { cnt[tid] = 0; deg[tid] = 0.f; cur[tid] = 0; }
    __syncthreads();
    int eb0 = beb[b], eb1 = beb[b + 1];
    for (int i = eb0 + tid; i < eb1; i += 256) {
        int4 t = stage[i];
        int j = t.z & 127;
        atomicAdd(&cnt[j], 1);
        atomicAdd(&deg[j], __int_as_float(t.y));
    }
    __syncthreads();
    if (tid < 128) sc[tid] = cnt[tid];
    __syncthreads();
    for (int off = 1; off < 128; off <<= 1) {
        int v = 0;
        if (tid < 128 && tid >= off) v = sc[tid - off];
        __syncthreads();
        if (tid < 128) sc[tid] += v;
        __syncthreads();
    }
    if (tid < 128) {
        int n = b * 128 + tid;
        int ex = tid ? sc[tid - 1] : 0;
        if (n <= NN) row_ptr[n] = eb0 + ex;   // n==NN writes the end sentinel (=NE)
        if (n < NN) {
            float di = rsqrtf(deg[tid] + 1.0f);
            dinv[n] = di;
            float4 a, bb;
            a.x = di * x[n * IND + 0]; a.y = di * x[n * IND + 1];
            a.z = di * x[n * IND + 2]; a.w = di * x[n * IND + 3];
            bb.x = di * x[n * IND + 4]; bb.y = 0.f; bb.z = 0.f; bb.w = 0.f;
            ((float4*)px)[n * 2 + 0] = a;
            ((float4*)px)[n * 2 + 1] = bb;
        }
    }
    __syncthreads();
    for (int i = eb0 + tid; i < eb1; i += 256) {
        int4 t = stage[i];
        int j = t.z & 127;
        int ex = j ? sc[j - 1] : 0;
        int off = atomicAdd(&cur[j], 1);
        csr[eb0 + ex + off] = make_int2(t.x, t.y);
    }
}

// ---- layer-1 aggregation on pre-scaled raw x ----
__global__ void k_gather_x(const float* __restrict__ px, const float* __restrict__ dinv,
                           const int* __restrict__ row_ptr, const int2* __restrict__ csr,
                           float* __restrict__ xa) {
    int gid = blockIdx.x * blockDim.x + threadIdx.x;  // NN*16 threads
    if (gid >= NN * 16) return;
    int n = gid >> 4, lane16 = gid & 15;
    const float4* p4 = (const float4*)px;
    int beg = row_ptr[n], end = row_ptr[n + 1];
    float4 a0 = make_float4(0.f, 0.f, 0.f, 0.f);
    float a4 = 0.f;
    int i = beg + lane16;
    if (i < end) {
        long long cur = __builtin_nontemporal_load((const long long*)&csr[i]);
        for (; i < end; i += 16) {
            int pi = (i + 16 < end) ? i + 16 : i;
            long long nxt = __builtin_nontemporal_load((const long long*)&csr[pi]);
            int   s = (int)(cur & 0xffffffffLL);
            float w = __int_as_float((int)(cur >> 32));
            float4 v0 = p4[s * 2 + 0];
            float  v4 = px[s * 8 + 4];
            a0.x += w * v0.x; a0.y += w * v0.y; a0.z += w * v0.z; a0.w += w * v0.w;
            a4 += w * v4;
            cur = nxt;
        }
    }
#pragma unroll
    for (int m = 8; m >= 1; m >>= 1) {
        a0.x += __shfl_xor(a0.x, m); a0.y += __shfl_xor(a0.y, m);
        a0.z += __shfl_xor(a0.z, m); a0.w += __shfl_xor(a0.w, m);
        a4 += __shfl_xor(a4, m);
    }
    if (lane16 == 0) {
        float di = dinv[n];
        float4 v0 = p4[n * 2 + 0];
        float  v4 = px[n * 8 + 4];
        float4 o0;
        o0.x = di * (a0.x + v0.x); o0.y = di * (a0.y + v0.y);
        o0.z = di * (a0.z + v0.z); o0.w = di * (a0.w + v0.w);
        ((float4*)xa)[n * 2 + 0] = o0;
        ((float4*)xa)[n * 2 + 1] = make_float4(di * (a4 + v4), 0.f, 0.f, 0.f);
    }
}

// ---- fused projection + bias + bn1 + relu ----
__global__ void k_gemm1_fused(const float* __restrict__ xa, const float* __restrict__ W1,
                              const float* __restrict__ b1,
                              const float* __restrict__ gamma, const float* __restrict__ beta,
                              const float* __restrict__ mean, const float* __restrict__ var,
                              float* __restrict__ outv) {
    __shared__ float Ws[IND * HID];
    for (int j = threadIdx.x; j < IND * HID; j += blockDim.x) Ws[j] = W1[j];
    __syncthreads();
    int gid = blockIdx.x * blockDim.x + threadIdx.x;
    if (gid >= NN * HID) return;
    int n = gid >> 6, hc = gid & 63;
    const float* xr = &xa[n * 8];
    float acc = b1[hc];
#pragma unroll
    for (int k = 0; k < IND; k++) acc += xr[k] * Ws[k * HID + hc];
    float r = fmaxf((acc - mean[hc]) * rsqrtf(var[hc] + EPSV) * gamma[hc] + beta[hc], 0.f);
    outv[gid] = r;
}

// ---- a @ W2, pre-scaled by dinv[n], fp16 full-width table (128 B/row) ----
__global__ void k_gemm2_h16(const float* __restrict__ a, const float* __restrict__ W,
                            const float* __restrict__ dinv, __half* __restrict__ tab) {
    __shared__ float Ws[HID * HID];
    for (int j = threadIdx.x; j < HID * HID; j += blockDim.x) Ws[j] = W[j];
    __syncthreads();
    int gid = blockIdx.x * blockDim.x + threadIdx.x;
    if (gid >= NN * HID) return;
    int n = gid >> 6, hc = gid & 63;
    const float* ar = &a[n * HID];
    float acc = 0.f;
#pragma unroll 8
    for (int k = 0; k < HID; k++) acc += ar[k] * Ws[k * HID + hc];
    tab[gid] = __float2half(dinv[n] * acc);
}

// ---- layer-2 gather (16 lanes/node, uint2/lane, 2-DEEP edge unroll: two
//      independent feature loads + two csr prefetches in flight per chain;
//      retest of R6's unroll now that the atomic tail is gone) + bn2 + relu
//      + per-block LDS segmented pool reduction ----
__global__ void k_gather_pool(const __half* __restrict__ tab, const float* __restrict__ dinv,
                              const int* __restrict__ row_ptr, const int2* __restrict__ csr,
                              const float* __restrict__ bias,
                              const float* __restrict__ gamma, const float* __restrict__ beta,
                              const float* __restrict__ mean, const float* __restrict__ var,
                              const int* __restrict__ batch,
                              float* pool, float* cnt) {
    __shared__ float lds[16 * HID];
    __shared__ int gs[16];
    int tid = threadIdx.x;
    int gid = blockIdx.x * blockDim.x + tid;   // NN*16 threads exactly
    int n = gid >> 4, c4 = gid & 15;
    int nl = tid >> 4;
    if (tid < 16) gs[tid] = batch[blockIdx.x * 16 + tid];

    const uint2* hq = (const uint2*)tab;
    int beg = row_ptr[n], end = row_ptr[n + 1];

    uint2 sraw = hq[n * 16 + c4];
    float2 s01 = __half22float2(*(const __half2*)&sraw.x);
    float2 s23 = __half22float2(*(const __half2*)&sraw.y);
    float a0 = s01.x, a1 = s01.y, a2 = s23.x, a3 = s23.y;

    if (beg < end) {
        int i = beg;
        long long c0l = __builtin_nontemporal_load((const long long*)&csr[i]);
        long long c1l = (i + 1 < end) ? __builtin_nontemporal_load((const long long*)&csr[i + 1]) : 0;
        for (; i + 2 <= end; i += 2) {
            long long p0 = (i + 2 < end) ? __builtin_nontemporal_load((const long long*)&csr[i + 2]) : 0;
            long long p1 = (i + 3 < end) ? __builtin_nontemporal_load((const long long*)&csr[i + 3]) : 0;
            int   s0 = (int)(c0l & 0xffffffffLL);
            float w0 = __int_as_float((int)(c0l >> 32));
            int   s1 = (int)(c1l & 0xffffffffLL);
            float w1 = __int_as_float((int)(c1l >> 32));
            uint2 r0 = hq[s0 * 16 + c4];            // two independent loads
            uint2 r1 = hq[s1 * 16 + c4];
            float2 f;
            f = __half22float2(*(const __half2*)&r0.x); a0 += w0 * f.x; a1 += w0 * f.y;
            f = __half22float2(*(const __half2*)&r0.y); a2 += w0 * f.x; a3 += w0 * f.y;
            f = __half22float2(*(const __half2*)&r1.x); a0 += w1 * f.x; a1 += w1 * f.y;
            f = __half22float2(*(const __half2*)&r1.y); a2 += w1 * f.x; a3 += w1 * f.y;
            c0l = p0; c1l = p1;
        }
        if (i < end) {                               // odd remainder (entry in c0l)
            int   s0 = (int)(c0l & 0xffffffffLL);
            float w0 = __int_as_float((int)(c0l >> 32));
            uint2 r0 = hq[s0 * 16 + c4];
            float2 f;
            f = __half22float2(*(const __half2*)&r0.x); a0 += w0 * f.x; a1 += w0 * f.y;
            f = __half22float2(*(const __half2*)&r0.y); a2 += w0 * f.x; a3 += w0 * f.y;
        }
    }

    float di = dinv[n];
    int c0 = c4 * 4;
    float4 r;
    {
        float v0 = di * a0 + bias[c0 + 0];
        float v1 = di * a1 + bias[c0 + 1];
        float v2 = di * a2 + bias[c0 + 2];
        float v3 = di * a3 + bias[c0 + 3];
        r.x = fmaxf((v0 - mean[c0 + 0]) * rsqrtf(var[c0 + 0] + EPSV) * gamma[c0 + 0] + beta[c0 + 0], 0.f);
        r.y = fmaxf((v1 - mean[c0 + 1]) * rsqrtf(var[c0 + 1] + EPSV) * gamma[c0 + 1] + beta[c0 + 1], 0.f);
        r.z = fmaxf((v2 - mean[c0 + 2]) * rsqrtf(var[c0 + 2] + EPSV) * gamma[c0 + 2] + beta[c0 + 2], 0.f);
        r.w = fmaxf((v3 - mean[c0 + 3]) * rsqrtf(var[c0 + 3] + EPSV) * gamma[c0 + 3] + beta[c0 + 3], 0.f);
    }
    ((float4*)lds)[nl * 16 + c4] = r;
    __syncthreads();

    if (tid < HID) {
        int c = tid;
        float run = lds[0 * HID + c];
        int gprev = gs[0];
#pragma unroll
        for (int node = 1; node < 16; node++) {
            int g = gs[node];
            float v = lds[node * HID + c];
            if (g != gprev) { atomicAdd(&pool[gprev * HID + c], run); run = v; gprev = g; }
            else run += v;
        }
        atomicAdd(&pool[gprev * HID + c], run);
    } else if (tid == HID) {
        int run = 1, gprev = gs[0];
        for (int node = 1; node < 16; node++) {
            int g = gs[node];
            if (g != gprev) { atomicAdd(&cnt[gprev], (float)run); run = 0; gprev = g; }
            run++;
        }
        atomicAdd(&cnt[gprev], (float)run);
    }
}

// ---- final MLP: one wave per graph ----
__global__ void k_mlp(const float* __restrict__ pool_sums, const float* __restrict__ cnt,
                      const float* __restrict__ l1W, const float* __restrict__ l1b,
                      const float* __restrict__ l2W, const float* __restrict__ l2b,
                      float* __restrict__ outp) {
    int g = blockIdx.x;
    int lane = threadIdx.x;           // 64
    int j = lane & 31, kh = lane >> 5;
    const float* pg = &pool_sums[g * HID];
    float z = 0.f;
#pragma unroll 8
    for (int k = kh * 32; k < kh * 32 + 32; k++)
        z += pg[k] * l1W[k * (HID / 2) + j];
    z += __shfl_xor(z, 32);           // join k-halves
    float inv = 1.0f / fmaxf(cnt[g], 1.0f);
    float acc = (kh == 0) ? fmaxf(z * inv + l1b[j], 0.f) * l2W[j] : 0.f;
#pragma unroll
    for (int m = 16; m >= 1; m >>= 1) acc += __shfl_xor(acc, m);
    if (lane == 0) outp[g] = acc + l2b[0];
}

extern "C" void kernel_launch(void* const* d_in, const int* in_sizes, int n_in,
                              void* d_out, int out_size, void* d_ws, size_t ws_size,
                              hipStream_t stream) {
    const float* x   = (const float*)d_in[0];
    const int*   ei  = (const int*)d_in[1];
    const float* ew  = (const float*)d_in[2];
    const int*   bat = (const int*)d_in[3];
    const float* W1  = (const float*)d_in[4];
    const float* b1  = (const float*)d_in[5];
    const float* W2  = (const float*)d_in[6];
    const float* b2  = (const float*)d_in[7];
    const float* g1  = (const float*)d_in[8];
    const float* be1 = (const float*)d_in[9];
    const float* m1  = (const float*)d_in[10];
    const float* v1  = (const float*)d_in[11];
    const float* g2  = (const float*)d_in[12];
    const float* be2 = (const float*)d_in[13];
    const float* m2  = (const float*)d_in[14];
    const float* v2  = (const float*)d_in[15];
    const float* l1W = (const float*)d_in[16];
    const float* l1b = (const float*)d_in[17];
    const float* l2W = (const float*)d_in[18];
    const float* l2b = (const float*)d_in[19];
    float* out = (float*)d_out;

    const int* src = ei;
    const int* dst = ei + NE;

    // ---- workspace layout (4-byte units) ----
    float* f = (float*)d_ws;
    float* pool      = f + 0;                  // 8192
    float* cnt       = f + 8192;               // 128
    int*   bkt_hist  = (int*)(f + 8320);       // 391
    int*   bkt_cur   = (int*)(f + 8711);       // 391
    // zero region = [0, 9104) floats
    int*   beb       = (int*)(f + 9104);       // 392 (fully written by bscan)
    int*   row_ptr   = (int*)(f + 9496);       // 50001 (fully written by bucket_fill)
    int2*  csr       = (int2*)(f + 59500);     // 800000 int2 -> ends 1659500
    float* dinv      = f + 1659500;            // 50000
    float* px        = f + 1709500;            // NN*8 -> 2109500
    float* xa        = f + 2109500;            // NN*8 -> 2509500
    float* bufC      = f + 2509504;            // NN*HID fp32 (aliases stage; stage dead
    int4*  stage     = (int4*)(f + 2509504);   //  before gemm1 writes bufC) -> 5709504
    __half* tab      = (__half*)(f + 5709504); // NN*HID fp16 -> ends 7309504 (29.2 MB)

    const int BLK = 256;
    const int gNH  = (NN * HID + BLK - 1) / BLK;
    const int gN16 = (NN * 16 + BLK - 1) / BLK;   // 3125 blocks

    hipMemsetAsync(d_ws, 0, 9104 * sizeof(float), stream);

    // CSR build: bucket-partitioned (391 buckets x 128 nodes), all L2-local
    k_part_hist<<<PH_WG, PH_T, 0, stream>>>(dst, bkt_hist);
    k_bscan<<<1, 512, 0, stream>>>(bkt_hist, beb);
    k_part_scatter<<<PH_WG, PH_T, 0, stream>>>(src, dst, ew, beb, bkt_cur, stage);
    k_bucket_fill<<<NB, BLK, 0, stream>>>(stage, beb, x, row_ptr, csr, dinv, px);

    // layer 1: pre-scaled raw-x aggregation, then project (+bias+bn1+relu fused)
    k_gather_x<<<gN16, BLK, 0, stream>>>(px, dinv, row_ptr, csr, xa);
    k_gemm1_fused<<<gNH, BLK, 0, stream>>>(xa, W1, b1, g1, be1, m1, v1, bufC);

    // layer 2: project to pre-scaled fp16 table, fused gather + bn2 + relu + LDS pool
    k_gemm2_h16<<<gNH, BLK, 0, stream>>>(bufC, W2, dinv, tab);
    k_gather_pool<<<gN16, BLK, 0, stream>>>(tab, dinv, row_ptr, csr, b2,
                                            g2, be2, m2, v2, bat, pool, cnt);

    // MLP head: one wave per graph
    k_mlp<<<NG, 64, 0, stream>>>(pool, cnt, l1W, l1b, l2W, l2b, out);
}

// Round 14
// 136.040 us; speedup vs baseline: 5.3790x; 1.2186x over previous
//
#include <hip/hip_runtime.h>
#include <hip/hip_fp16.h>

#define NN 50000
#define NE 800000
#define NG 128
#define IND 5
#define HID 64
#define EPSV 1e-5f

#define NB 391          // buckets of 128 nodes: 391*128 = 50048 >= 50001
#define PH_T 1024       // partition wg size
#define PH_E 16384      // edges per partition wg (49 wgs)
#define PH_WG ((NE + PH_E - 1) / PH_E)

// ---- partition pass 1: per-bucket edge counts (LDS hist -> ~19k global atomics) ----
__global__ void k_part_hist(const int* __restrict__ dst, int* __restrict__ bkt_hist) {
    __shared__ int h[NB];
    int tid = threadIdx.x;
    for (int j = tid; j < NB; j += PH_T) h[j] = 0;
    __syncthreads();
    int base = blockIdx.x * PH_E;
    for (int k = 0; k < PH_E; k += PH_T) {
        int e = base + k + tid;
        if (e < NE) atomicAdd(&h[dst[e] >> 7], 1);
    }
    __syncthreads();
    for (int j = tid; j < NB; j += PH_T) if (h[j]) atomicAdd(&bkt_hist[j], h[j]);
}

// ---- tiny scan of 391 bucket counts -> exclusive bucket edge bases beb[0..391] ----
__global__ void k_bscan(const int* __restrict__ bkt_hist, int* __restrict__ beb) {
    __shared__ int sm[512];
    int t = threadIdx.x;
    sm[t] = (t < NB) ? bkt_hist[t] : 0;
    __syncthreads();
    for (int off = 1; off < 512; off <<= 1) {
        int v = (t >= off) ? sm[t - off] : 0;
        __syncthreads();
        sm[t] += v;
        __syncthreads();
    }
    if (t <= NB) beb[t] = t ? sm[t - 1] : 0;
}

// ---- partition pass 2: scatter edges into bucket-contiguous staging ----
__global__ void k_part_scatter(const int* __restrict__ src, const int* __restrict__ dst,
                               const float* __restrict__ ew, const int* __restrict__ beb,
                               int* __restrict__ bkt_cursor, int4* __restrict__ stage) {
    __shared__ int c[NB];
    __shared__ int base[NB];
    __shared__ int cur[NB];
    int tid = threadIdx.x;
    for (int j = tid; j < NB; j += PH_T) { c[j] = 0; cur[j] = 0; }
    __syncthreads();
    int eb = blockIdx.x * PH_E;
    for (int k = 0; k < PH_E; k += PH_T) {
        int e = eb + k + tid;
        if (e < NE) atomicAdd(&c[dst[e] >> 7], 1);
    }
    __syncthreads();
    for (int j = tid; j < NB; j += PH_T) base[j] = c[j] ? atomicAdd(&bkt_cursor[j], c[j]) : 0;
    __syncthreads();
    for (int k = 0; k < PH_E; k += PH_T) {
        int e = eb + k + tid;
        if (e < NE) {
            int d = dst[e], b = d >> 7;
            int off = atomicAdd(&cur[b], 1);
            stage[beb[b] + base[b] + off] = make_int4(src[e], __float_as_int(ew[e]), d, 0);
        }
    }
}

// ---- bucket finalize: row_ptr + dinv + px + in-window csr scatter ----
__global__ void k_bucket_fill(const int4* __restrict__ stage, const int* __restrict__ beb,
                              const float* __restrict__ x,
                              int* __restrict__ row_ptr, int2* __restrict__ csr,
                              float* __restrict__ dinv, float* __restrict__ px) {
    __shared__ int cnt[128];
    __shared__ float deg[128];
    __shared__ int cur[128];
    __shared__ int sc[128];
    int b = blockIdx.x, tid = threadIdx.x;
    if (tid < 128) { cnt[tid] = 0; deg[tid] = 0.f; cur[tid] = 0; }
    __syncthreads();
    int eb0 = beb[b], eb1 = beb[b + 1];
    for (int i = eb0 + tid; i < eb1; i += 256) {
        int4 t = stage[i];
        int j = t.z & 127;
        atomicAdd(&cnt[j], 1);
        atomicAdd(&deg[j], __int_as_float(t.y));
    }
    __syncthreads();
    if (tid < 128) sc[tid] = cnt[tid];
    __syncthreads();
    for (int off = 1; off < 128; off <<= 1) {
        int v = 0;
        if (tid < 128 && tid >= off) v = sc[tid - off];
        __syncthreads();
        if (tid < 128) sc[tid] += v;
        __syncthreads();
    }
    if (tid < 128) {
        int n = b * 128 + tid;
        int ex = tid ? sc[tid - 1] : 0;
        if (n <= NN) row_ptr[n] = eb0 + ex;   // n==NN writes the end sentinel (=NE)
        if (n < NN) {
            float di = rsqrtf(deg[tid] + 1.0f);
            dinv[n] = di;
            float4 a, bb;
            a.x = di * x[n * IND + 0]; a.y = di * x[n * IND + 1];
            a.z = di * x[n * IND + 2]; a.w = di * x[n * IND + 3];
            bb.x = di * x[n * IND + 4]; bb.y = 0.f; bb.z = 0.f; bb.w = 0.f;
            ((float4*)px)[n * 2 + 0] = a;
            ((float4*)px)[n * 2 + 1] = bb;
        }
    }
    __syncthreads();
    for (int i = eb0 + tid; i < eb1; i += 256) {
        int4 t = stage[i];
        int j = t.z & 127;
        int ex = j ? sc[j - 1] : 0;
        int off = atomicAdd(&cur[j], 1);
        csr[eb0 + ex + off] = make_int2(t.x, t.y);
    }
}

// ---- layer-1 aggregation on pre-scaled raw x ----
__global__ void k_gather_x(const float* __restrict__ px, const float* __restrict__ dinv,
                           const int* __restrict__ row_ptr, const int2* __restrict__ csr,
                           float* __restrict__ xa) {
    int gid = blockIdx.x * blockDim.x + threadIdx.x;  // NN*16 threads
    if (gid >= NN * 16) return;
    int n = gid >> 4, lane16 = gid & 15;
    const float4* p4 = (const float4*)px;
    int beg = row_ptr[n], end = row_ptr[n + 1];
    float4 a0 = make_float4(0.f, 0.f, 0.f, 0.f);
    float a4 = 0.f;
    int i = beg + lane16;
    if (i < end) {
        long long cur = __builtin_nontemporal_load((const long long*)&csr[i]);
        for (; i < end; i += 16) {
            int pi = (i + 16 < end) ? i + 16 : i;
            long long nxt = __builtin_nontemporal_load((const long long*)&csr[pi]);
            int   s = (int)(cur & 0xffffffffLL);
            float w = __int_as_float((int)(cur >> 32));
            float4 v0 = p4[s * 2 + 0];
            float  v4 = px[s * 8 + 4];
            a0.x += w * v0.x; a0.y += w * v0.y; a0.z += w * v0.z; a0.w += w * v0.w;
            a4 += w * v4;
            cur = nxt;
        }
    }
#pragma unroll
    for (int m = 8; m >= 1; m >>= 1) {
        a0.x += __shfl_xor(a0.x, m); a0.y += __shfl_xor(a0.y, m);
        a0.z += __shfl_xor(a0.z, m); a0.w += __shfl_xor(a0.w, m);
        a4 += __shfl_xor(a4, m);
    }
    if (lane16 == 0) {
        float di = dinv[n];
        float4 v0 = p4[n * 2 + 0];
        float  v4 = px[n * 8 + 4];
        float4 o0;
        o0.x = di * (a0.x + v0.x); o0.y = di * (a0.y + v0.y);
        o0.z = di * (a0.z + v0.z); o0.w = di * (a0.w + v0.w);
        ((float4*)xa)[n * 2 + 0] = o0;
        ((float4*)xa)[n * 2 + 1] = make_float4(di * (a4 + v4), 0.f, 0.f, 0.f);
    }
}

// ---- fused projection + bias + bn1 + relu ----
__global__ void k_gemm1_fused(const float* __restrict__ xa, const float* __restrict__ W1,
                              const float* __restrict__ b1,
                              const float* __restrict__ gamma, const float* __restrict__ beta,
                              const float* __restrict__ mean, const float* __restrict__ var,
                              float* __restrict__ outv) {
    __shared__ float Ws[IND * HID];
    for (int j = threadIdx.x; j < IND * HID; j += blockDim.x) Ws[j] = W1[j];
    __syncthreads();
    int gid = blockIdx.x * blockDim.x + threadIdx.x;
    if (gid >= NN * HID) return;
    int n = gid >> 6, hc = gid & 63;
    const float* xr = &xa[n * 8];
    float acc = b1[hc];
#pragma unroll
    for (int k = 0; k < IND; k++) acc += xr[k] * Ws[k * HID + hc];
    float r = fmaxf((acc - mean[hc]) * rsqrtf(var[hc] + EPSV) * gamma[hc] + beta[hc], 0.f);
    outv[gid] = r;
}

// ---- a @ W2 -> fp16 table.  Thread = (n, q): 4 channels, 4 INDEPENDENT FMA
//      chains (old version: 1 chain, 64 dependent FMAs -> VALUBusy 25%).
//      a-row read as 16 broadcast float4; W staged as float4 (b128 LDS). ----
__global__ void k_gemm2_h16(const float* __restrict__ a, const float* __restrict__ W,
                            const float* __restrict__ dinv, __half* __restrict__ tab) {
    __shared__ float4 Ws4[HID * 16];   // W[k][4q..4q+3]
    {
        const float4* W4 = (const float4*)W;
        for (int j = threadIdx.x; j < HID * 16; j += blockDim.x) Ws4[j] = W4[j];
    }
    __syncthreads();
    int gid = blockIdx.x * blockDim.x + threadIdx.x;   // NN*16 threads
    if (gid >= NN * 16) return;
    int n = gid >> 4, q = gid & 15;
    const float4* ar4 = (const float4*)&a[n * HID];
    float acc0 = 0.f, acc1 = 0.f, acc2 = 0.f, acc3 = 0.f;
#pragma unroll
    for (int k4 = 0; k4 < 16; k4++) {
        float4 av = ar4[k4];                 // broadcast across the 16 q-lanes
        float4 w0 = Ws4[(k4 * 4 + 0) * 16 + q];
        float4 w1 = Ws4[(k4 * 4 + 1) * 16 + q];
        float4 w2 = Ws4[(k4 * 4 + 2) * 16 + q];
        float4 w3 = Ws4[(k4 * 4 + 3) * 16 + q];
        acc0 += av.x * w0.x + av.y * w1.x + av.z * w2.x + av.w * w3.x;
        acc1 += av.x * w0.y + av.y * w1.y + av.z * w2.y + av.w * w3.y;
        acc2 += av.x * w0.z + av.y * w1.z + av.z * w2.z + av.w * w3.z;
        acc3 += av.x * w0.w + av.y * w1.w + av.z * w2.w + av.w * w3.w;
    }
    float di = dinv[n];
    __half2 h01 = __floats2half2_rn(di * acc0, di * acc1);
    __half2 h23 = __floats2half2_rn(di * acc2, di * acc3);
    uint2 packed;
    packed.x = *(const unsigned int*)&h01;
    packed.y = *(const unsigned int*)&h23;
    ((uint2*)tab)[gid] = packed;
}

// ---- layer-2 gather (16 lanes/node, uint2/lane, 2-deep edge unroll) + bn2 +
//      relu + per-block LDS segmented pool reduction ----
__global__ void k_gather_pool(const __half* __restrict__ tab, const float* __restrict__ dinv,
                              const int* __restrict__ row_ptr, const int2* __restrict__ csr,
                              const float* __restrict__ bias,
                              const float* __restrict__ gamma, const float* __restrict__ beta,
                              const float* __restrict__ mean, const float* __restrict__ var,
                              const int* __restrict__ batch,
                              float* pool, float* cnt) {
    __shared__ float lds[16 * HID];
    __shared__ int gs[16];
    int tid = threadIdx.x;
    int gid = blockIdx.x * blockDim.x + tid;   // NN*16 threads exactly
    int n = gid >> 4, c4 = gid & 15;
    int nl = tid >> 4;
    if (tid < 16) gs[tid] = batch[blockIdx.x * 16 + tid];

    const uint2* hq = (const uint2*)tab;
    int beg = row_ptr[n], end = row_ptr[n + 1];

    uint2 sraw = hq[n * 16 + c4];
    float2 s01 = __half22float2(*(const __half2*)&sraw.x);
    float2 s23 = __half22float2(*(const __half2*)&sraw.y);
    float a0 = s01.x, a1 = s01.y, a2 = s23.x, a3 = s23.y;

    if (beg < end) {
        int i = beg;
        long long c0l = __builtin_nontemporal_load((const long long*)&csr[i]);
        long long c1l = (i + 1 < end) ? __builtin_nontemporal_load((const long long*)&csr[i + 1]) : 0;
        for (; i + 2 <= end; i += 2) {
            long long p0 = (i + 2 < end) ? __builtin_nontemporal_load((const long long*)&csr[i + 2]) : 0;
            long long p1 = (i + 3 < end) ? __builtin_nontemporal_load((const long long*)&csr[i + 3]) : 0;
            int   s0 = (int)(c0l & 0xffffffffLL);
            float w0 = __int_as_float((int)(c0l >> 32));
            int   s1 = (int)(c1l & 0xffffffffLL);
            float w1 = __int_as_float((int)(c1l >> 32));
            uint2 r0 = hq[s0 * 16 + c4];            // two independent loads
            uint2 r1 = hq[s1 * 16 + c4];
            float2 f;
            f = __half22float2(*(const __half2*)&r0.x); a0 += w0 * f.x; a1 += w0 * f.y;
            f = __half22float2(*(const __half2*)&r0.y); a2 += w0 * f.x; a3 += w0 * f.y;
            f = __half22float2(*(const __half2*)&r1.x); a0 += w1 * f.x; a1 += w1 * f.y;
            f = __half22float2(*(const __half2*)&r1.y); a2 += w1 * f.x; a3 += w1 * f.y;
            c0l = p0; c1l = p1;
        }
        if (i < end) {                               // odd remainder (entry in c0l)
            int   s0 = (int)(c0l & 0xffffffffLL);
            float w0 = __int_as_float((int)(c0l >> 32));
            uint2 r0 = hq[s0 * 16 + c4];
            float2 f;
            f = __half22float2(*(const __half2*)&r0.x); a0 += w0 * f.x; a1 += w0 * f.y;
            f = __half22float2(*(const __half2*)&r0.y); a2 += w0 * f.x; a3 += w0 * f.y;
        }
    }

    float di = dinv[n];
    int c0 = c4 * 4;
    float4 r;
    {
        float v0 = di * a0 + bias[c0 + 0];
        float v1 = di * a1 + bias[c0 + 1];
        float v2 = di * a2 + bias[c0 + 2];
        float v3 = di * a3 + bias[c0 + 3];
        r.x = fmaxf((v0 - mean[c0 + 0]) * rsqrtf(var[c0 + 0] + EPSV) * gamma[c0 + 0] + beta[c0 + 0], 0.f);
        r.y = fmaxf((v1 - mean[c0 + 1]) * rsqrtf(var[c0 + 1] + EPSV) * gamma[c0 + 1] + beta[c0 + 1], 0.f);
        r.z = fmaxf((v2 - mean[c0 + 2]) * rsqrtf(var[c0 + 2] + EPSV) * gamma[c0 + 2] + beta[c0 + 2], 0.f);
        r.w = fmaxf((v3 - mean[c0 + 3]) * rsqrtf(var[c0 + 3] + EPSV) * gamma[c0 + 3] + beta[c0 + 3], 0.f);
    }
    ((float4*)lds)[nl * 16 + c4] = r;
    __syncthreads();

    if (tid < HID) {
        int c = tid;
        float run = lds[0 * HID + c];
        int gprev = gs[0];
#pragma unroll
        for (int node = 1; node < 16; node++) {
            int g = gs[node];
            float v = lds[node * HID + c];
            if (g != gprev) { atomicAdd(&pool[gprev * HID + c], run); run = v; gprev = g; }
            else run += v;
        }
        atomicAdd(&pool[gprev * HID + c], run);
    } else if (tid == HID) {
        int run = 1, gprev = gs[0];
        for (int node = 1; node < 16; node++) {
            int g = gs[node];
            if (g != gprev) { atomicAdd(&cnt[gprev], (float)run); run = 0; gprev = g; }
            run++;
        }
        atomicAdd(&cnt[gprev], (float)run);
    }
}

// ---- final MLP: one wave per graph ----
__global__ void k_mlp(const float* __restrict__ pool_sums, const float* __restrict__ cnt,
                      const float* __restrict__ l1W, const float* __restrict__ l1b,
                      const float* __restrict__ l2W, const float* __restrict__ l2b,
                      float* __restrict__ outp) {
    int g = blockIdx.x;
    int lane = threadIdx.x;           // 64
    int j = lane & 31, kh = lane >> 5;
    const float* pg = &pool_sums[g * HID];
    float z = 0.f;
#pragma unroll 8
    for (int k = kh * 32; k < kh * 32 + 32; k++)
        z += pg[k] * l1W[k * (HID / 2) + j];
    z += __shfl_xor(z, 32);           // join k-halves
    float inv = 1.0f / fmaxf(cnt[g], 1.0f);
    float acc = (kh == 0) ? fmaxf(z * inv + l1b[j], 0.f) * l2W[j] : 0.f;
#pragma unroll
    for (int m = 16; m >= 1; m >>= 1) acc += __shfl_xor(acc, m);
    if (lane == 0) outp[g] = acc + l2b[0];
}

extern "C" void kernel_launch(void* const* d_in, const int* in_sizes, int n_in,
                              void* d_out, int out_size, void* d_ws, size_t ws_size,
                              hipStream_t stream) {
    const float* x   = (const float*)d_in[0];
    const int*   ei  = (const int*)d_in[1];
    const float* ew  = (const float*)d_in[2];
    const int*   bat = (const int*)d_in[3];
    const float* W1  = (const float*)d_in[4];
    const float* b1  = (const float*)d_in[5];
    const float* W2  = (const float*)d_in[6];
    const float* b2  = (const float*)d_in[7];
    const float* g1  = (const float*)d_in[8];
    const float* be1 = (const float*)d_in[9];
    const float* m1  = (const float*)d_in[10];
    const float* v1  = (const float*)d_in[11];
    const float* g2  = (const float*)d_in[12];
    const float* be2 = (const float*)d_in[13];
    const float* m2  = (const float*)d_in[14];
    const float* v2  = (const float*)d_in[15];
    const float* l1W = (const float*)d_in[16];
    const float* l1b = (const float*)d_in[17];
    const float* l2W = (const float*)d_in[18];
    const float* l2b = (const float*)d_in[19];
    float* out = (float*)d_out;

    const int* src = ei;
    const int* dst = ei + NE;

    // ---- workspace layout (4-byte units) ----
    float* f = (float*)d_ws;
    float* pool      = f + 0;                  // 8192
    float* cnt       = f + 8192;               // 128
    int*   bkt_hist  = (int*)(f + 8320);       // 391
    int*   bkt_cur   = (int*)(f + 8711);       // 391
    // zero region = [0, 9104) floats
    int*   beb       = (int*)(f + 9104);       // 392 (fully written by bscan)
    int*   row_ptr   = (int*)(f + 9496);       // 50001 (fully written by bucket_fill)
    int2*  csr       = (int2*)(f + 59500);     // 800000 int2 -> ends 1659500
    float* dinv      = f + 1659500;            // 50000
    float* px        = f + 1709500;            // NN*8 -> 2109500
    float* xa        = f + 2109500;            // NN*8 -> 2509500
    float* bufC      = f + 2509504;            // NN*HID fp32 (aliases stage; stage dead
    int4*  stage     = (int4*)(f + 2509504);   //  before gemm1 writes bufC) -> 5709504
    __half* tab      = (__half*)(f + 5709504); // NN*HID fp16 -> ends 7309504 (29.2 MB)

    const int BLK = 256;
    const int gNH  = (NN * HID + BLK - 1) / BLK;
    const int gN16 = (NN * 16 + BLK - 1) / BLK;   // 3125 blocks

    hipMemsetAsync(d_ws, 0, 9104 * sizeof(float), stream);

    // CSR build: bucket-partitioned (391 buckets x 128 nodes), all L2-local
    k_part_hist<<<PH_WG, PH_T, 0, stream>>>(dst, bkt_hist);
    k_bscan<<<1, 512, 0, stream>>>(bkt_hist, beb);
    k_part_scatter<<<PH_WG, PH_T, 0, stream>>>(src, dst, ew, beb, bkt_cur, stage);
    k_bucket_fill<<<NB, BLK, 0, stream>>>(stage, beb, x, row_ptr, csr, dinv, px);

    // layer 1: pre-scaled raw-x aggregation, then project (+bias+bn1+relu fused)
    k_gather_x<<<gN16, BLK, 0, stream>>>(px, dinv, row_ptr, csr, xa);
    k_gemm1_fused<<<gNH, BLK, 0, stream>>>(xa, W1, b1, g1, be1, m1, v1, bufC);

    // layer 2: project to pre-scaled fp16 table (4-chain ILP), gather+pool
    k_gemm2_h16<<<gN16, BLK, 0, stream>>>(bufC, W2, dinv, tab);
    k_gather_pool<<<gN16, BLK, 0, stream>>>(tab, dinv, row_ptr, csr, b2,
                                            g2, be2, m2, v2, bat, pool, cnt);

    // MLP head: one wave per graph
    k_mlp<<<NG, 64, 0, stream>>>(pool, cnt, l1W, l1b, l2W, l2b, out);
}